// Round 12
// baseline (133.042 us; speedup 1.0000x reference)
//
#include <hip/hip_runtime.h>
#include <hip/hip_bf16.h>
#include <stdint.h>

using u16 = unsigned short;
using u32 = unsigned int;
using u8  = unsigned char;

#define NB 64
#define TT 128
#define DK 768
#define MC 30

typedef float f32x16 __attribute__((ext_vector_type(16)));
typedef __bf16 bf16x8 __attribute__((ext_vector_type(8)));
typedef long long ll;
typedef __attribute__((ext_vector_type(2))) ll ll2;

__device__ inline void unpack2(u32 u, float& lo, float& hi){
  union{u32 i; float f;} a, b; a.i = u << 16; b.i = u & 0xFFFF0000u; lo = a.f; hi = b.f;
}
__device__ inline u16 f2bf(float f){
  union{u32 i; float f;} v; v.f = f;
  u32 r = v.i + 0x7FFFu + ((v.i >> 16) & 1u);
  return (u16)(r >> 16);
}
__device__ inline u32 pack2bf(float a, float b){ return (u32)f2bf(a) | ((u32)f2bf(b) << 16); }

// ---------------- fp8 e4m3fn pack/unpack helpers ----------------
#if __has_builtin(__builtin_amdgcn_cvt_pk_fp8_f32)
template<bool HIW>
__device__ inline u32 pk_fp8(float a, float b, u32 old){
  return (u32)__builtin_amdgcn_cvt_pk_fp8_f32(a, b, (int)old, HIW);
}
#else
__device__ inline u8 f2fp8_1(float f){
  union{float f; u32 u;} v; v.f = f;
  u32 s = (v.u >> 24) & 0x80u;
  u32 abs = v.u & 0x7fffffffu;
  if (abs < 0x3c800000u){
    float sc = fabsf(f) * 512.0f;
    int m = (int)rintf(sc);
    return (u8)(s | (u32)m);
  }
  u32 e8 = abs >> 23; u32 mant = abs & 0x7fffffu;
  u32 m3 = mant >> 20; u32 rest = mant & 0xfffffu;
  u32 rb = (rest > 0x80000u) || (rest == 0x80000u && (m3 & 1u));
  m3 += rb;
  u32 E = e8 - 120u;
  if (m3 == 8u){ m3 = 0u; E += 1u; }
  if (E >= 16u || (E == 15u && m3 == 7u)) return (u8)(s | 0x7Eu);
  return (u8)(s | (E << 3) | m3);
}
template<bool HIW>
__device__ inline u32 pk_fp8(float a, float b, u32 old){
  u32 w = (u32)f2fp8_1(a) | ((u32)f2fp8_1(b) << 8);
  return HIW ? ((old & 0x0000FFFFu) | (w << 16)) : ((old & 0xFFFF0000u) | w);
}
#endif

#if __has_builtin(__builtin_amdgcn_cvt_pk_f32_fp8)
__device__ inline void upk_fp8x4(u32 w, float* x){
  auto a0 = __builtin_amdgcn_cvt_pk_f32_fp8((int)w, false);
  auto a1 = __builtin_amdgcn_cvt_pk_f32_fp8((int)w, true);
  x[0] = a0[0]; x[1] = a0[1]; x[2] = a1[0]; x[3] = a1[1];
}
#else
__device__ inline float fp8_1(u32 byte){
  u32 s = (byte & 0x80u) << 24;
  u32 E = (byte >> 3) & 15u, M = byte & 7u;
  union{u32 u; float f;} v;
  if (E == 0){ v.f = (float)M * (1.0f/512.0f); v.u |= s; }
  else v.u = s | ((E + 120u) << 23) | (M << 20);
  return v.f;
}
__device__ inline void upk_fp8x4(u32 w, float* x){
  x[0] = fp8_1(w & 255u); x[1] = fp8_1((w >> 8) & 255u);
  x[2] = fp8_1((w >> 16) & 255u); x[3] = fp8_1(w >> 24);
}
#endif

// ---------------- weight prep ----------------
// w2p: fp8 [tap][oc32][ic32], intra-page bytes pre-swizzled with ^((oc&7)<<4)
// w1c: bf16 MFMA A-frag table [dy][oc32][k16], k = dx*2 + c (dx>=5 zero), swizzled
__global__ __launch_bounds__(256) void prep_w_k(const float* __restrict__ w2,
    const float* __restrict__ w1, u8* __restrict__ w2p, u16* __restrict__ w1c){
  int bidx = blockIdx.x;
  if (bidx < 25){
    int tap = bidx;
    int i = threadIdx.x;
    int oc = i >> 3, q = i & 7, ic0 = q * 4;
    float v[4];
    #pragma unroll
    for (int j = 0; j < 4; ++j)
      v[j] = (oc < MC && ic0 + j < MC) ? w2[(oc*MC + ic0 + j)*25 + tap] : 0.f;
    u32 w = pk_fp8<false>(v[0], v[1], 0u);
    w = pk_fp8<true>(v[2], v[3], w);
    int lo = ((oc << 5) + (q << 2)) ^ ((oc & 7) << 4);
    *(u32*)(w2p + tap*1024 + lo) = w;
  } else {
    for (int i = threadIdx.x; i < 2560; i += 256){
      int dy = i >> 9; int rem = i & 511; int oc = rem >> 4; int k = rem & 15;
      int dx = k >> 1, c = k & 1;
      float v = (oc < MC && dx < 5) ? w1[(oc*2 + c)*25 + dy*5 + dx] : 0.f;
      int byteoff = dy*1024 + (((oc<<5) + (k<<1)) ^ ((oc&7)<<4));
      *(u16*)((char*)w1c + byteoff) = f2bf(v);
    }
  }
}

// ---------------- kernel 1: row norms + bf16 conversion ----------------
__global__ __launch_bounds__(256) void row_norms_k(const float* __restrict__ q, const float* __restrict__ k,
    float* __restrict__ qq, float* __restrict__ kk,
    u16* __restrict__ qb16, u16* __restrict__ kb16){
  int wave = blockIdx.x * 4 + (threadIdx.x >> 6);
  int lane = threadIdx.x & 63;
  const float* src; float* dst; u16* bdst; int row;
  if (wave < NB * TT) { src = q; dst = qq; bdst = qb16; row = wave; }
  else                { src = k; dst = kk; bdst = kb16; row = wave - NB * TT; }
  const float4* p = (const float4*)(src + (size_t)row * DK + lane * 12);
  u16* ob = bdst + (size_t)row * DK + lane * 12;
  float s = 0.f;
  #pragma unroll
  for (int t = 0; t < 3; ++t){
    float4 v = p[t];
    s += v.x*v.x + v.y*v.y + v.z*v.z + v.w*v.w;
    uint2 st; st.x = pack2bf(v.x, v.y); st.y = pack2bf(v.z, v.w);
    *(uint2*)(ob + t*4) = st;
  }
  #pragma unroll
  for (int o = 32; o; o >>= 1) s += __shfl_xor(s, o);
  if (lane == 0) dst[row] = s;
}

// ---------------- kernel 2: cdist via bf16 MFMA, double-buffered K staging ----------------
// inb output: u32 per (b,y,x): lo = bf16(D), hi = bf16(P)
__global__ __launch_bounds__(256) void cdist_mfma_k(
    const u16* __restrict__ Qb16, const u16* __restrict__ Kb16,
    const float* __restrict__ qq, const float* __restrict__ kk,
    const int* __restrict__ qlen, const int* __restrict__ klen,
    const float* __restrict__ qR, const float* __restrict__ kR,
    float* __restrict__ Dout, u32* __restrict__ inb){
  __shared__ __align__(16) char qs[32 * 1536];       // 48KB Q tile, swizzled
  __shared__ __align__(16) char ksm[2][128 * 256];   // 2 x 32KB K chunks, swizzled
  int rt = blockIdx.x;
  int b  = blockIdx.y;
  int r0 = rt * 32;
  int tid = threadIdx.x;
  const u16* Qg = Qb16 + ((size_t)b * TT + r0) * DK;
  const u16* Kg = Kb16 + (size_t)b * TT * DK;
  for (int idx = tid; idx < 3072; idx += 256){
    int row = idx / 96, ch = idx - row * 96;
    uint4 v = *(const uint4*)(Qg + row * DK + ch * 8);
    *(uint4*)(qs + row * 1536 + ((ch * 16) ^ ((row & 7) << 4))) = v;
  }
  for (int idx = tid; idx < 2048; idx += 256){
    int c = idx >> 4, j = idx & 15;
    uint4 v = *(const uint4*)(Kg + c * DK + j * 8);
    *(uint4*)(ksm[0] + c * 256 + ((j * 16) ^ ((c & 7) << 4))) = v;
  }
  __syncthreads();
  int lane = tid & 63, w = tid >> 6;
  int hi = lane >> 5, l31 = lane & 31;
  int col = w * 32 + l31;
  f32x16 acc;
  #pragma unroll
  for (int r = 0; r < 16; ++r) acc[r] = 0.f;
  for (int ch = 0; ch < 6; ++ch){
    int cur = ch & 1;
    if (ch < 5){
      int kcn = (ch + 1) * 128;
      for (int idx = tid; idx < 2048; idx += 256){
        int c = idx >> 4, j = idx & 15;
        uint4 v = *(const uint4*)(Kg + c * DK + kcn + j * 8);
        *(uint4*)(ksm[cur ^ 1] + c * 256 + ((j * 16) ^ ((c & 7) << 4))) = v;
      }
    }
    int kc = ch * 128;
    #pragma unroll
    for (int k8 = 0; k8 < 8; ++k8){
      bf16x8 a  = *(const bf16x8*)(qs + l31 * 1536 + (((kc + k8*16 + hi*8) * 2) ^ ((l31 & 7) << 4)));
      bf16x8 bv = *(const bf16x8*)(ksm[cur] + col * 256 + (((k8*16 + hi*8) * 2) ^ ((col & 7) << 4)));
      acc = __builtin_amdgcn_mfma_f32_32x32x16_bf16(a, bv, acc, 0, 0, 0);
    }
    __syncthreads();
  }
  int ql = qlen[b], kl = klen[b];
  float kkv = kk[b * TT + col];
  float krv = kR[b * TT + col];
  bool cm = col < kl;
  #pragma unroll
  for (int r = 0; r < 16; ++r){
    int row = r0 + (r & 3) + 8 * (r >> 2) + 4 * hi;
    float qqv = qq[b * TT + row];
    float sq = qqv + kkv - 2.f * acc[r];
    float d = sqrtf(fmaxf(sq, 1e-12f));
    bool m = (row < ql) && cm;
    float dm = m ? d : 0.f;
    float pm = m ? fabsf(qR[b * TT + row] - krv) : 0.f;
    Dout[(((size_t)b * TT + row) << 7) + col] = dm;
    inb[(((size_t)b * TT + row) << 7) + col] = pack2bf(dm, pm);
  }
}

// ---------------- conv1: 2ch -> 30ch 5x5 via bf16 MFMA, fp8 out [b][y][x][c32] ----------------
#define C1_ROWW 136
__global__ __launch_bounds__(512, 2) void conv1_mfma_k(const u32* __restrict__ inb,
    const u16* __restrict__ w1c, const float* __restrict__ bias, u8* __restrict__ act1){
  __shared__ u32 ilds[12 * C1_ROWW];
  __shared__ __align__(16) char wlds[5120];
  __shared__ __align__(16) char tr[8 * 4096];
  int yg = blockIdx.x, bb = blockIdx.y;
  int y0 = yg * 8, tid = threadIdx.x;
  {
    const uint4* src = (const uint4*)w1c;
    uint4* dst = (uint4*)wlds;
    for (int i = tid; i < 320; i += 512) dst[i] = src[i];
  }
  for (int i = tid; i < 12 * C1_ROWW; i += 512){
    int r = i / C1_ROWW, xi = i - r * C1_ROWW;
    int gy = y0 - 2 + r, gx = xi - 2;
    u32 v = 0;
    if ((unsigned)gy < 128u && (unsigned)gx < 128u)
      v = inb[(((size_t)bb * 128 + gy) << 7) + gx];
    ilds[r * C1_ROWW + xi] = v;
  }
  __syncthreads();
  int lane = tid & 63, w = tid >> 6;
  int hi = lane >> 5, l31 = lane & 31;
  bf16x8 afr[5];
  #pragma unroll
  for (int dy = 0; dy < 5; ++dy)
    afr[dy] = *(const bf16x8*)(wlds + dy*1024 + (((l31<<5) + (hi<<4)) ^ ((l31&7)<<4)));
  float biasv[16];
  #pragma unroll
  for (int r = 0; r < 16; ++r){
    int oc = (r & 3) + 8*(r >> 2) + 4*hi;
    biasv[r] = (oc < MC) ? bias[oc] : 0.f;
  }
  int wbase = w * 4096;
  #pragma unroll
  for (int t = 0; t < 4; ++t){
    int px = t*32 + l31;
    f32x16 acc;
    #pragma unroll
    for (int r = 0; r < 16; ++r) acc[r] = 0.f;
    #pragma unroll
    for (int dy = 0; dy < 5; ++dy){
      const u32* rp = &ilds[(w + dy)*C1_ROWW + px + hi*4];
      union { u32 uw[4]; bf16x8 v; } ub;
      ub.uw[0] = rp[0]; ub.uw[1] = rp[1]; ub.uw[2] = rp[2]; ub.uw[3] = rp[3];
      acc = __builtin_amdgcn_mfma_f32_32x32x16_bf16(afr[dy], ub.v, acc, 0, 0, 0);
    }
    #pragma unroll
    for (int q = 0; q < 4; ++q){
      float v0 = fmaxf(acc[4*q+0] + biasv[4*q+0], 0.f);
      float v1 = fmaxf(acc[4*q+1] + biasv[4*q+1], 0.f);
      float v2 = fmaxf(acc[4*q+2] + biasv[4*q+2], 0.f);
      float v3 = fmaxf(acc[4*q+3] + biasv[4*q+3], 0.f);
      u32 word = pk_fp8<false>(v0, v1, 0u);
      word = pk_fp8<true>(v2, v3, word);
      int addr = wbase + (((px<<5) + (q<<3) + (hi<<2)) ^ ((px&7)<<3));
      *(u32*)(tr + addr) = word;
    }
  }
  int y = y0 + w;
  #pragma unroll
  for (int p = 0; p < 8; ++p){
    int x = p*16 + (lane >> 2), cg = lane & 3;
    int addr = wbase + (((x<<5) + (cg<<3)) ^ ((x&7)<<3));
    uint2 v = *(const uint2*)(tr + addr);
    *(uint2*)(act1 + ((((size_t)bb*128 + y)*128 + x) << 5) + cg*8) = v;
  }
}

// ---------------- conv2: 30->30 5x5 via fp8 MFMA, 2 output rows per wave ----------------
#define C2_IN_ROWB 4224                 // 132 px * 32 B
#define C2_IN_BYTES (12*C2_IN_ROWB)     // 50688
#define C2_W_OFF C2_IN_BYTES
#define C2_SMEM (C2_W_OFF + 25*1024)    // 76288

__global__ __launch_bounds__(256, 2) void conv2_mfma_k(
    const u8* __restrict__ act1, const u8* __restrict__ w2p,
    const float* __restrict__ bias, u8* __restrict__ act2){
  __shared__ __align__(16) char smem[C2_SMEM];
  int yg = blockIdx.x;          // 0..15
  int bb = blockIdx.y;
  int y0 = yg * 8;
  int tid = threadIdx.x;
  // weights: linear copy (layout pre-swizzled in prep_w_k)
  {
    const uint4* src = (const uint4*)w2p;
    uint4* dst = (uint4*)(smem + C2_W_OFF);
    for (int i = tid; i < 1600; i += 256) dst[i] = src[i];
  }
  // stage input rows y0-2 .. y0+9 : [r][x132][ic32] fp8, XOR-swizzled
  for (int i = tid; i < 3168; i += 256){
    int r = i / 264; int t2 = i - r*264; int lx = t2 >> 1; int h = t2 & 1;
    int gy = y0 - 2 + r, gx = lx - 2;
    uint4 v = make_uint4(0,0,0,0);
    if ((unsigned)gy < 128u && (unsigned)gx < 128u)
      v = *(const uint4*)(act1 + ((((size_t)(bb*128 + gy)*128 + gx)) << 5) + (h << 4));
    int boff = ((lx << 5) + (h << 4)) ^ ((lx & 7) << 4);
    *(uint4*)(smem + r*C2_IN_ROWB + boff) = v;
  }
  __syncthreads();
  int lane = tid & 63, w = tid >> 6;   // w in 0..3: out rows y0+2w, y0+2w+1
  int hi = lane >> 5, l31 = lane & 31;
  int aSwz = ((l31 << 5) + (hi << 4)) ^ ((l31 & 7) << 4);
  f32x16 acc0[4], acc1[4];
  #pragma unroll
  for (int t = 0; t < 4; ++t)
    #pragma unroll
    for (int r = 0; r < 16; ++r){ acc0[t][r] = 0.f; acc1[t][r] = 0.f; }
  ll2 aCur[5], aPrev[5];
  #pragma unroll
  for (int rr = 0; rr < 6; ++rr){
    if (rr < 5){
      #pragma unroll
      for (int dx = 0; dx < 5; ++dx)
        aCur[dx] = *(const ll2*)(smem + C2_W_OFF + ((rr*5 + dx) << 10) + aSwz);
    }
    const char* rowp = smem + (2*w + rr)*C2_IN_ROWB;
    #pragma unroll
    for (int dx = 0; dx < 5; ++dx){
      #pragma unroll
      for (int t = 0; t < 4; ++t){
        int px2 = t*32 + l31 + dx;
        int boff = ((px2 << 5) + (hi << 4)) ^ ((px2 & 7) << 4);
        ll2 b = *(const ll2*)(rowp + boff);
        if (rr < 5){
          acc0[t] = __builtin_amdgcn_mfma_f32_32x32x16_fp8_fp8(aCur[dx].x, b.x, acc0[t], 0, 0, 0);
          acc0[t] = __builtin_amdgcn_mfma_f32_32x32x16_fp8_fp8(aCur[dx].y, b.y, acc0[t], 0, 0, 0);
        }
        if (rr >= 1){
          acc1[t] = __builtin_amdgcn_mfma_f32_32x32x16_fp8_fp8(aPrev[dx].x, b.x, acc1[t], 0, 0, 0);
          acc1[t] = __builtin_amdgcn_mfma_f32_32x32x16_fp8_fp8(aPrev[dx].y, b.y, acc1[t], 0, 0, 0);
        }
      }
    }
    #pragma unroll
    for (int dx = 0; dx < 5; ++dx) aPrev[dx] = aCur[dx];
  }
  float biasv[16];
  #pragma unroll
  for (int r = 0; r < 16; ++r){
    int oc = (r & 3) + 8*(r >> 2) + 4*hi;
    biasv[r] = (oc < MC) ? bias[oc] : 0.f;
  }
  __syncthreads();   // all LDS reads done before overwriting with transpose
  // transpose via LDS: wave w uses 8KB at w*8192 (4KB per output row)
  #pragma unroll
  for (int rI = 0; rI < 2; ++rI){
    int wbase = w * 8192 + rI * 4096;
    #pragma unroll
    for (int t = 0; t < 4; ++t){
      int px = t*32 + l31;
      #pragma unroll
      for (int q = 0; q < 4; ++q){
        float v0 = fmaxf((rI ? acc1[t][4*q+0] : acc0[t][4*q+0]) + biasv[4*q+0], 0.f);
        float v1 = fmaxf((rI ? acc1[t][4*q+1] : acc0[t][4*q+1]) + biasv[4*q+1], 0.f);
        float v2 = fmaxf((rI ? acc1[t][4*q+2] : acc0[t][4*q+2]) + biasv[4*q+2], 0.f);
        float v3 = fmaxf((rI ? acc1[t][4*q+3] : acc0[t][4*q+3]) + biasv[4*q+3], 0.f);
        u32 word = pk_fp8<false>(v0, v1, 0u);
        word = pk_fp8<true>(v2, v3, word);
        int addr = wbase + (((px<<5) + (q<<3) + (hi<<2)) ^ (((px>>2)&3)<<3));
        *(u32*)(smem + addr) = word;
      }
    }
  }
  #pragma unroll
  for (int rI = 0; rI < 2; ++rI){
    int y = y0 + 2*w + rI;
    int wbase = w * 8192 + rI * 4096;
    #pragma unroll
    for (int p = 0; p < 8; ++p){
      int x = p*16 + (lane >> 2), cg = lane & 3;
      int addr = wbase + (((x<<5) + (cg<<3)) ^ (((x>>2)&3)<<3));
      uint2 v = *(const uint2*)(smem + addr);
      *(uint2*)(act2 + ((((size_t)bb*128 + y)*128 + x) << 5) + cg*8) = v;
    }
  }
}

// ---------------- conv3 + mask + row softmax + A write + row D*A ----------------
__global__ __launch_bounds__(512) void conv3sm_k(const u8* __restrict__ act2,
    const float* __restrict__ w3, const float* __restrict__ b3, const float* __restrict__ Dbuf,
    const int* __restrict__ qlen, const int* __restrict__ klen,
    float* __restrict__ Aout, float* __restrict__ rowsum, int b0){
  __shared__ float wlds[9][32];
  __shared__ float ex0[512], ex2[512];
  __shared__ float redm[8], reds[8], redd[8];
  int i  = blockIdx.x;
  int bb = blockIdx.y;
  int b  = b0 + bb;
  int tid = threadIdx.x;
  for (int idx = tid; idx < 288; idx += 512){
    int tap = idx >> 5, c = idx & 31;
    wlds[tap][c] = (c < MC) ? w3[c * 9 + tap] : 0.f;
  }
  __syncthreads();
  int px = tid >> 2, cg = tid & 3, wv = tid >> 6;
  float T0 = 0.f, T1 = 0.f, T2 = 0.f;
  #pragma unroll
  for (int dy = 0; dy < 3; ++dy){
    int gy = i - 1 + dy;
    uint2 v = make_uint2(0, 0);
    if ((unsigned)gy < 128u)
      v = *(const uint2*)(act2 + ((((size_t)bb*128 + gy)*128 + px) << 5) + cg*8);
    float x[8];
    upk_fp8x4(v.x, x);
    upk_fp8x4(v.y, x + 4);
    const float* w0p = &wlds[dy*3 + 0][cg*8];
    const float* w1p = &wlds[dy*3 + 1][cg*8];
    const float* w2q = &wlds[dy*3 + 2][cg*8];
    #pragma unroll
    for (int c = 0; c < 8; ++c){
      T0 = fmaf(x[c], w0p[c], T0);
      T1 = fmaf(x[c], w1p[c], T1);
      T2 = fmaf(x[c], w2q[c], T2);
    }
  }
  ex0[tid] = T0; ex2[tid] = T2;
  __syncthreads();
  float acc = T1;
  if (px > 0)   acc += ex0[tid - 4];
  if (px < 127) acc += ex2[tid + 4];
  acc += __shfl_xor(acc, 1);
  acc += __shfl_xor(acc, 2);
  acc += b3[0];
  float Dv = Dbuf[(((size_t)b * 128 + i) << 7) + px];
  bool m = (i < qlen[b]) && (px < klen[b]);
  float xv = m ? -(acc + Dv) : -100.f;
  float mx = xv;
  #pragma unroll
  for (int o = 32; o; o >>= 1) mx = fmaxf(mx, __shfl_xor(mx, o));
  if ((tid & 63) == 0) redm[wv] = mx;
  __syncthreads();
  mx = fmaxf(fmaxf(fmaxf(redm[0], redm[1]), fmaxf(redm[2], redm[3])),
             fmaxf(fmaxf(redm[4], redm[5]), fmaxf(redm[6], redm[7])));
  float e = __expf(xv - mx);
  float s  = e;
  float de = Dv * e;
  #pragma unroll
  for (int o = 32; o; o >>= 1){ s += __shfl_xor(s, o); de += __shfl_xor(de, o); }
  if ((tid & 63) == 0){ reds[wv] = s; redd[wv] = de; }
  __syncthreads();
  float s8  = (reds[0] + reds[1]) + (reds[2] + reds[3]) + (reds[4] + reds[5]) + (reds[6] + reds[7]);
  float a = e * 4.0f / s8;
  if (cg == 0) Aout[(((size_t)b * 128 + i) << 7) + px] = a;
  if (tid == 0){
    float d8 = (redd[0] + redd[1]) + (redd[2] + redd[3]) + (redd[4] + redd[5]) + (redd[6] + redd[7]);
    rowsum[b * TT + i] = d8 / s8;
  }
}

// ---------------- dis reduce ----------------
__global__ __launch_bounds__(128) void dis_k(const float* __restrict__ rowsum, float* __restrict__ out){
  int b = blockIdx.x, tid = threadIdx.x;
  float v = rowsum[b * TT + tid];
  #pragma unroll
  for (int o = 32; o; o >>= 1) v += __shfl_xor(v, o);
  __shared__ float red[2];
  if ((tid & 63) == 0) red[tid >> 6] = v;
  __syncthreads();
  if (tid == 0) out[b] = (red[0] + red[1]) * (1.0f / 128.0f);
}

extern "C" void kernel_launch(void* const* d_in, const int* in_sizes, int n_in,
                              void* d_out, int out_size, void* d_ws, size_t ws_size,
                              hipStream_t stream){
  const float* q_seq = (const float*)d_in[0];
  const int*   q_len = (const int*)d_in[1];
  const float* q_R   = (const float*)d_in[2];
  const float* k_seq = (const float*)d_in[3];
  const int*   k_len = (const int*)d_in[4];
  const float* k_R   = (const float*)d_in[5];
  const float* c1w   = (const float*)d_in[6];
  const float* c1b   = (const float*)d_in[7];
  const float* c2w   = (const float*)d_in[8];
  const float* c2b   = (const float*)d_in[9];
  const float* c3w   = (const float*)d_in[10];
  const float* c3b   = (const float*)d_in[11];
  float* out = (float*)d_out;

  char* base = (char*)d_ws;
  size_t off = 0;
  auto take = [&](size_t bytes)->char*{
    char* p = base + off;
    off = (off + bytes + 255) & ~(size_t)255;
    return p;
  };
  float* Dbuf   = (float*)take((size_t)NB * TT * TT * 4);
  float* qq     = (float*)take((size_t)NB * TT * 4);
  float* kkn    = (float*)take((size_t)NB * TT * 4);
  float* rowsum = (float*)take((size_t)NB * TT * 4);
  u32*   inb    = (u32*)  take((size_t)NB * TT * TT * 4);
  u8*    w2p    = (u8*)   take(25 * 1024);
  u16*   w1c    = (u16*)  take(5 * 1024);
  u16*   qb16   = (u16*)  take((size_t)NB * TT * DK * 2);
  u16*   kb16   = (u16*)  take((size_t)NB * TT * DK * 2);
  size_t fixed = off;
  int BCH = 64;
  while (BCH > 1 && fixed + (size_t)BCH * TT * TT * 64 + 1024 > ws_size) BCH >>= 1;
  u8* act1 = (u8*)take((size_t)BCH * TT * TT * 32);
  u8* act2 = (u8*)take((size_t)BCH * TT * TT * 32);

  prep_w_k<<<26, 256, 0, stream>>>(c2w, c1w, w2p, w1c);
  row_norms_k<<<4096, 256, 0, stream>>>(q_seq, k_seq, qq, kkn, qb16, kb16);
  cdist_mfma_k<<<dim3(4, NB), 256, 0, stream>>>(qb16, kb16, qq, kkn, q_len, k_len, q_R, k_R, Dbuf, inb);
  for (int b0 = 0; b0 < NB; b0 += BCH){
    int nb = BCH;
    conv1_mfma_k<<<dim3(16, nb), 512, 0, stream>>>(inb + (size_t)b0 * TT * TT, w1c, c1b, act1);
    conv2_mfma_k<<<dim3(16, nb), 256, 0, stream>>>(act1, w2p, c2b, act2);
    conv3sm_k<<<dim3(TT, nb), 512, 0, stream>>>(act2, c3w, c3b, Dbuf, q_len, k_len, out, rowsum, b0);
  }
  dis_k<<<NB, 128, 0, stream>>>(rowsum, out + (size_t)NB * TT * TT);
}

// Round 13
// 125.615 us; speedup vs baseline: 1.0591x; 1.0591x over previous
//
#include <hip/hip_runtime.h>
#include <hip/hip_bf16.h>
#include <stdint.h>

using u16 = unsigned short;
using u32 = unsigned int;
using u8  = unsigned char;

#define NB 64
#define TT 128
#define DK 768
#define MC 30

typedef float f32x16 __attribute__((ext_vector_type(16)));
typedef __bf16 bf16x8 __attribute__((ext_vector_type(8)));
typedef long long ll;
typedef __attribute__((ext_vector_type(2))) ll ll2;

__device__ inline void unpack2(u32 u, float& lo, float& hi){
  union{u32 i; float f;} a, b; a.i = u << 16; b.i = u & 0xFFFF0000u; lo = a.f; hi = b.f;
}
__device__ inline u16 f2bf(float f){
  union{u32 i; float f;} v; v.f = f;
  u32 r = v.i + 0x7FFFu + ((v.i >> 16) & 1u);
  return (u16)(r >> 16);
}
__device__ inline u32 pack2bf(float a, float b){ return (u32)f2bf(a) | ((u32)f2bf(b) << 16); }

// ---------------- fp8 e4m3fn pack/unpack helpers ----------------
#if __has_builtin(__builtin_amdgcn_cvt_pk_fp8_f32)
template<bool HIW>
__device__ inline u32 pk_fp8(float a, float b, u32 old){
  return (u32)__builtin_amdgcn_cvt_pk_fp8_f32(a, b, (int)old, HIW);
}
#else
__device__ inline u8 f2fp8_1(float f){
  union{float f; u32 u;} v; v.f = f;
  u32 s = (v.u >> 24) & 0x80u;
  u32 abs = v.u & 0x7fffffffu;
  if (abs < 0x3c800000u){
    float sc = fabsf(f) * 512.0f;
    int m = (int)rintf(sc);
    return (u8)(s | (u32)m);
  }
  u32 e8 = abs >> 23; u32 mant = abs & 0x7fffffu;
  u32 m3 = mant >> 20; u32 rest = mant & 0xfffffu;
  u32 rb = (rest > 0x80000u) || (rest == 0x80000u && (m3 & 1u));
  m3 += rb;
  u32 E = e8 - 120u;
  if (m3 == 8u){ m3 = 0u; E += 1u; }
  if (E >= 16u || (E == 15u && m3 == 7u)) return (u8)(s | 0x7Eu);
  return (u8)(s | (E << 3) | m3);
}
template<bool HIW>
__device__ inline u32 pk_fp8(float a, float b, u32 old){
  u32 w = (u32)f2fp8_1(a) | ((u32)f2fp8_1(b) << 8);
  return HIW ? ((old & 0x0000FFFFu) | (w << 16)) : ((old & 0xFFFF0000u) | w);
}
#endif

#if __has_builtin(__builtin_amdgcn_cvt_pk_f32_fp8)
__device__ inline void upk_fp8x4(u32 w, float* x){
  auto a0 = __builtin_amdgcn_cvt_pk_f32_fp8((int)w, false);
  auto a1 = __builtin_amdgcn_cvt_pk_f32_fp8((int)w, true);
  x[0] = a0[0]; x[1] = a0[1]; x[2] = a1[0]; x[3] = a1[1];
}
#else
__device__ inline float fp8_1(u32 byte){
  u32 s = (byte & 0x80u) << 24;
  u32 E = (byte >> 3) & 15u, M = byte & 7u;
  union{u32 u; float f;} v;
  if (E == 0){ v.f = (float)M * (1.0f/512.0f); v.u |= s; }
  else v.u = s | ((E + 120u) << 23) | (M << 20);
  return v.f;
}
__device__ inline void upk_fp8x4(u32 w, float* x){
  x[0] = fp8_1(w & 255u); x[1] = fp8_1((w >> 8) & 255u);
  x[2] = fp8_1((w >> 16) & 255u); x[3] = fp8_1(w >> 24);
}
#endif

// ---------------- weight prep ----------------
// w2p: fp8 [tap][oc32][ic32], intra-page bytes pre-swizzled with ^((oc&7)<<4)
// w1c: bf16 MFMA A-frag table [dy][oc32][k16], k = dx*2 + c (dx>=5 zero), swizzled
__global__ __launch_bounds__(256) void prep_w_k(const float* __restrict__ w2,
    const float* __restrict__ w1, u8* __restrict__ w2p, u16* __restrict__ w1c){
  int bidx = blockIdx.x;
  if (bidx < 25){
    int tap = bidx;
    int i = threadIdx.x;
    int oc = i >> 3, q = i & 7, ic0 = q * 4;
    float v[4];
    #pragma unroll
    for (int j = 0; j < 4; ++j)
      v[j] = (oc < MC && ic0 + j < MC) ? w2[(oc*MC + ic0 + j)*25 + tap] : 0.f;
    u32 w = pk_fp8<false>(v[0], v[1], 0u);
    w = pk_fp8<true>(v[2], v[3], w);
    int lo = ((oc << 5) + (q << 2)) ^ ((oc & 7) << 4);
    *(u32*)(w2p + tap*1024 + lo) = w;
  } else {
    for (int i = threadIdx.x; i < 2560; i += 256){
      int dy = i >> 9; int rem = i & 511; int oc = rem >> 4; int k = rem & 15;
      int dx = k >> 1, c = k & 1;
      float v = (oc < MC && dx < 5) ? w1[(oc*2 + c)*25 + dy*5 + dx] : 0.f;
      int byteoff = dy*1024 + (((oc<<5) + (k<<1)) ^ ((oc&7)<<4));
      *(u16*)((char*)w1c + byteoff) = f2bf(v);
    }
  }
}

// ---------------- kernel 1: row norms + bf16 conversion ----------------
__global__ __launch_bounds__(256) void row_norms_k(const float* __restrict__ q, const float* __restrict__ k,
    float* __restrict__ qq, float* __restrict__ kk,
    u16* __restrict__ qb16, u16* __restrict__ kb16){
  int wave = blockIdx.x * 4 + (threadIdx.x >> 6);
  int lane = threadIdx.x & 63;
  const float* src; float* dst; u16* bdst; int row;
  if (wave < NB * TT) { src = q; dst = qq; bdst = qb16; row = wave; }
  else                { src = k; dst = kk; bdst = kb16; row = wave - NB * TT; }
  const float4* p = (const float4*)(src + (size_t)row * DK + lane * 12);
  u16* ob = bdst + (size_t)row * DK + lane * 12;
  float s = 0.f;
  #pragma unroll
  for (int t = 0; t < 3; ++t){
    float4 v = p[t];
    s += v.x*v.x + v.y*v.y + v.z*v.z + v.w*v.w;
    uint2 st; st.x = pack2bf(v.x, v.y); st.y = pack2bf(v.z, v.w);
    *(uint2*)(ob + t*4) = st;
  }
  #pragma unroll
  for (int o = 32; o; o >>= 1) s += __shfl_xor(s, o);
  if (lane == 0) dst[row] = s;
}

// ---------------- kernel 2: cdist via bf16 MFMA + P + mask (round-11 proven) ----------------
// inb output: u32 per (b,y,x): lo = bf16(D), hi = bf16(P)
__global__ __launch_bounds__(256) void cdist_mfma_k(
    const u16* __restrict__ Qb16, const u16* __restrict__ Kb16,
    const float* __restrict__ qq, const float* __restrict__ kk,
    const int* __restrict__ qlen, const int* __restrict__ klen,
    const float* __restrict__ qR, const float* __restrict__ kR,
    float* __restrict__ Dout, u32* __restrict__ inb){
  __shared__ __align__(16) char qs[32 * 1536];    // [32 rows][768 k] bf16, swizzled
  __shared__ __align__(16) char ksm[128 * 256];   // [128 cols][128 k] bf16, swizzled
  int rt = blockIdx.x;
  int b  = blockIdx.y;
  int r0 = rt * 32;
  int tid = threadIdx.x;
  const u16* Qg = Qb16 + ((size_t)b * TT + r0) * DK;
  const u16* Kg = Kb16 + (size_t)b * TT * DK;
  for (int idx = tid; idx < 3072; idx += 256){
    int row = idx / 96, ch = idx - row * 96;
    uint4 v = *(const uint4*)(Qg + row * DK + ch * 8);
    *(uint4*)(qs + row * 1536 + ((ch * 16) ^ ((row & 7) << 4))) = v;
  }
  int lane = tid & 63, w = tid >> 6;
  int hi = lane >> 5, l31 = lane & 31;
  int col = w * 32 + l31;
  f32x16 acc;
  #pragma unroll
  for (int r = 0; r < 16; ++r) acc[r] = 0.f;
  for (int kc = 0; kc < DK; kc += 128){
    __syncthreads();
    for (int idx = tid; idx < 2048; idx += 256){
      int c = idx >> 4, j = idx & 15;
      uint4 v = *(const uint4*)(Kg + c * DK + kc + j * 8);
      *(uint4*)(ksm + c * 256 + ((j * 16) ^ ((c & 7) << 4))) = v;
    }
    __syncthreads();
    #pragma unroll
    for (int k8 = 0; k8 < 8; ++k8){
      bf16x8 a  = *(const bf16x8*)(qs  + l31 * 1536 + (((kc + k8*16 + hi*8) * 2) ^ ((l31 & 7) << 4)));
      bf16x8 bv = *(const bf16x8*)(ksm + col * 256  + (((k8*16 + hi*8) * 2) ^ ((col & 7) << 4)));
      acc = __builtin_amdgcn_mfma_f32_32x32x16_bf16(a, bv, acc, 0, 0, 0);
    }
  }
  int ql = qlen[b], kl = klen[b];
  float kkv = kk[b * TT + col];
  float krv = kR[b * TT + col];
  bool cm = col < kl;
  #pragma unroll
  for (int r = 0; r < 16; ++r){
    int row = r0 + (r & 3) + 8 * (r >> 2) + 4 * hi;
    float qqv = qq[b * TT + row];
    float sq = qqv + kkv - 2.f * acc[r];
    float d = sqrtf(fmaxf(sq, 1e-12f));
    bool m = (row < ql) && cm;
    float dm = m ? d : 0.f;
    float pm = m ? fabsf(qR[b * TT + row] - krv) : 0.f;
    Dout[(((size_t)b * TT + row) << 7) + col] = dm;
    inb[(((size_t)b * TT + row) << 7) + col] = pack2bf(dm, pm);
  }
}

// ---------------- conv1: 2ch -> 30ch 5x5 via bf16 MFMA, fp8 out [b][y][x][c32] ----------------
#define C1_ROWW 136
__global__ __launch_bounds__(512, 2) void conv1_mfma_k(const u32* __restrict__ inb,
    const u16* __restrict__ w1c, const float* __restrict__ bias, u8* __restrict__ act1){
  __shared__ u32 ilds[12 * C1_ROWW];
  __shared__ __align__(16) char wlds[5120];
  __shared__ __align__(16) char tr[8 * 4096];
  int yg = blockIdx.x, bb = blockIdx.y;
  int y0 = yg * 8, tid = threadIdx.x;
  {
    const uint4* src = (const uint4*)w1c;
    uint4* dst = (uint4*)wlds;
    for (int i = tid; i < 320; i += 512) dst[i] = src[i];
  }
  for (int i = tid; i < 12 * C1_ROWW; i += 512){
    int r = i / C1_ROWW, xi = i - r * C1_ROWW;
    int gy = y0 - 2 + r, gx = xi - 2;
    u32 v = 0;
    if ((unsigned)gy < 128u && (unsigned)gx < 128u)
      v = inb[(((size_t)bb * 128 + gy) << 7) + gx];
    ilds[r * C1_ROWW + xi] = v;
  }
  __syncthreads();
  int lane = tid & 63, w = tid >> 6;
  int hi = lane >> 5, l31 = lane & 31;
  bf16x8 afr[5];
  #pragma unroll
  for (int dy = 0; dy < 5; ++dy)
    afr[dy] = *(const bf16x8*)(wlds + dy*1024 + (((l31<<5) + (hi<<4)) ^ ((l31&7)<<4)));
  float biasv[16];
  #pragma unroll
  for (int r = 0; r < 16; ++r){
    int oc = (r & 3) + 8*(r >> 2) + 4*hi;
    biasv[r] = (oc < MC) ? bias[oc] : 0.f;
  }
  int wbase = w * 4096;
  #pragma unroll
  for (int t = 0; t < 4; ++t){
    int px = t*32 + l31;
    f32x16 acc;
    #pragma unroll
    for (int r = 0; r < 16; ++r) acc[r] = 0.f;
    #pragma unroll
    for (int dy = 0; dy < 5; ++dy){
      const u32* rp = &ilds[(w + dy)*C1_ROWW + px + hi*4];
      union { u32 uw[4]; bf16x8 v; } ub;
      ub.uw[0] = rp[0]; ub.uw[1] = rp[1]; ub.uw[2] = rp[2]; ub.uw[3] = rp[3];
      acc = __builtin_amdgcn_mfma_f32_32x32x16_bf16(afr[dy], ub.v, acc, 0, 0, 0);
    }
    #pragma unroll
    for (int q = 0; q < 4; ++q){
      float v0 = fmaxf(acc[4*q+0] + biasv[4*q+0], 0.f);
      float v1 = fmaxf(acc[4*q+1] + biasv[4*q+1], 0.f);
      float v2 = fmaxf(acc[4*q+2] + biasv[4*q+2], 0.f);
      float v3 = fmaxf(acc[4*q+3] + biasv[4*q+3], 0.f);
      u32 word = pk_fp8<false>(v0, v1, 0u);
      word = pk_fp8<true>(v2, v3, word);
      int addr = wbase + (((px<<5) + (q<<3) + (hi<<2)) ^ ((px&7)<<3));
      *(u32*)(tr + addr) = word;
    }
  }
  int y = y0 + w;
  #pragma unroll
  for (int p = 0; p < 8; ++p){
    int x = p*16 + (lane >> 2), cg = lane & 3;
    int addr = wbase + (((x<<5) + (cg<<3)) ^ ((x&7)<<3));
    uint2 v = *(const uint2*)(tr + addr);
    *(uint2*)(act1 + ((((size_t)bb*128 + y)*128 + x) << 5) + cg*8) = v;
  }
}

// ---------------- conv2: 30->30 5x5 via fp8 MFMA (round-11 proven) + XCD-chunked yg ----------------
#define C2_IN_ROWB 4224                 // 132 px * 32 B
#define C2_IN_BYTES (12*C2_IN_ROWB)     // 50688
#define C2_W_OFF C2_IN_BYTES
#define C2_SMEM (C2_W_OFF + 25*1024)    // 76288

__global__ __launch_bounds__(512, 4) void conv2_mfma_k(
    const u8* __restrict__ act1, const u8* __restrict__ w2p,
    const float* __restrict__ bias, u8* __restrict__ act2){
  __shared__ __align__(16) char smem[C2_SMEM];
  int o  = blockIdx.x;                    // 0..15
  int yg = ((o & 7) << 1) + (o >> 3);     // XCD-chunked: XCD k gets yg {2k,2k+1}
  int bb = blockIdx.y;
  int y0 = yg * 8;
  int tid = threadIdx.x;
  // weights: linear copy (layout pre-swizzled in prep_w_k)
  {
    const uint4* src = (const uint4*)w2p;
    uint4* dst = (uint4*)(smem + C2_W_OFF);
    for (int i = tid; i < 1600; i += 512) dst[i] = src[i];
  }
  // stage input rows y0-2 .. y0+9 : [r][x132][ic32] fp8, XOR-swizzled
  for (int i = tid; i < 3168; i += 512){
    int r = i / 264; int t2 = i - r*264; int lx = t2 >> 1; int h = t2 & 1;
    int gy = y0 - 2 + r, gx = lx - 2;
    uint4 v = make_uint4(0,0,0,0);
    if ((unsigned)gy < 128u && (unsigned)gx < 128u)
      v = *(const uint4*)(act1 + ((((size_t)(bb*128 + gy)*128 + gx)) << 5) + (h << 4));
    int boff = ((lx << 5) + (h << 4)) ^ ((lx & 7) << 4);
    *(uint4*)(smem + r*C2_IN_ROWB + boff) = v;
  }
  __syncthreads();
  int lane = tid & 63, w = tid >> 6;
  int hi = lane >> 5, l31 = lane & 31;
  int aBase = C2_W_OFF + (((l31 << 5) + (hi << 4)) ^ ((l31 & 7) << 4));
  f32x16 acc[4];
  #pragma unroll
  for (int t = 0; t < 4; ++t)
    #pragma unroll
    for (int r = 0; r < 16; ++r) acc[t][r] = 0.f;
  #pragma unroll
  for (int dy = 0; dy < 5; ++dy){
    const char* rowp = smem + (w + dy)*C2_IN_ROWB;
    #pragma unroll
    for (int dx = 0; dx < 5; ++dx){
      ll2 a = *(const ll2*)(smem + aBase + (dy*5 + dx)*1024);
      #pragma unroll
      for (int t = 0; t < 4; ++t){
        int px2 = t*32 + l31 + dx;
        int boff = ((px2 << 5) + (hi << 4)) ^ ((px2 & 7) << 4);
        ll2 b = *(const ll2*)(rowp + boff);
        acc[t] = __builtin_amdgcn_mfma_f32_32x32x16_fp8_fp8(a.x, b.x, acc[t], 0, 0, 0);
        acc[t] = __builtin_amdgcn_mfma_f32_32x32x16_fp8_fp8(a.y, b.y, acc[t], 0, 0, 0);
      }
    }
  }
  float biasv[16];
  #pragma unroll
  for (int r = 0; r < 16; ++r){
    int oc = (r & 3) + 8*(r >> 2) + 4*hi;
    biasv[r] = (oc < MC) ? bias[oc] : 0.f;
  }
  __syncthreads();
  // transpose via LDS (per-wave 4KB region; 2-way-max swizzle)
  int wbase = w * 8192;
  #pragma unroll
  for (int t = 0; t < 4; ++t){
    int px = t*32 + l31;
    #pragma unroll
    for (int q = 0; q < 4; ++q){
      float v0 = fmaxf(acc[t][4*q+0] + biasv[4*q+0], 0.f);
      float v1 = fmaxf(acc[t][4*q+1] + biasv[4*q+1], 0.f);
      float v2 = fmaxf(acc[t][4*q+2] + biasv[4*q+2], 0.f);
      float v3 = fmaxf(acc[t][4*q+3] + biasv[4*q+3], 0.f);
      u32 word = pk_fp8<false>(v0, v1, 0u);
      word = pk_fp8<true>(v2, v3, word);
      int addr = wbase + (((px<<5) + (q<<3) + (hi<<2)) ^ (((px>>2)&3)<<3));
      *(u32*)(smem + addr) = word;
    }
  }
  int y = y0 + w;
  #pragma unroll
  for (int p = 0; p < 8; ++p){
    int x = p*16 + (lane >> 2), cg = lane & 3;
    int addr = wbase + (((x<<5) + (cg<<3)) ^ (((x>>2)&3)<<3));
    uint2 v = *(const uint2*)(smem + addr);
    *(uint2*)(act2 + ((((size_t)bb*128 + y)*128 + x) << 5) + cg*8) = v;
  }
}

// ---------------- conv3 + mask + row softmax + A write + row D*A (+ XCD-chunked i) ----------------
__global__ __launch_bounds__(512) void conv3sm_k(const u8* __restrict__ act2,
    const float* __restrict__ w3, const float* __restrict__ b3, const float* __restrict__ Dbuf,
    const int* __restrict__ qlen, const int* __restrict__ klen,
    float* __restrict__ Aout, float* __restrict__ rowsum, int b0){
  __shared__ float wlds[9][32];
  __shared__ float ex0[512], ex2[512];
  __shared__ float redm[8], reds[8], redd[8];
  int o  = blockIdx.x;                    // 0..127
  int i  = ((o & 7) << 4) + (o >> 3);     // XCD-chunked: XCD k gets rows [16k,16k+16)
  int bb = blockIdx.y;
  int b  = b0 + bb;
  int tid = threadIdx.x;
  for (int idx = tid; idx < 288; idx += 512){
    int tap = idx >> 5, c = idx & 31;
    wlds[tap][c] = (c < MC) ? w3[c * 9 + tap] : 0.f;
  }
  __syncthreads();
  int px = tid >> 2, cg = tid & 3, wv = tid >> 6;
  float T0 = 0.f, T1 = 0.f, T2 = 0.f;
  #pragma unroll
  for (int dy = 0; dy < 3; ++dy){
    int gy = i - 1 + dy;
    uint2 v = make_uint2(0, 0);
    if ((unsigned)gy < 128u)
      v = *(const uint2*)(act2 + ((((size_t)bb*128 + gy)*128 + px) << 5) + cg*8);
    float x[8];
    upk_fp8x4(v.x, x);
    upk_fp8x4(v.y, x + 4);
    const float* w0p = &wlds[dy*3 + 0][cg*8];
    const float* w1p = &wlds[dy*3 + 1][cg*8];
    const float* w2q = &wlds[dy*3 + 2][cg*8];
    #pragma unroll
    for (int c = 0; c < 8; ++c){
      T0 = fmaf(x[c], w0p[c], T0);
      T1 = fmaf(x[c], w1p[c], T1);
      T2 = fmaf(x[c], w2q[c], T2);
    }
  }
  ex0[tid] = T0; ex2[tid] = T2;
  __syncthreads();
  float acc = T1;
  if (px > 0)   acc += ex0[tid - 4];
  if (px < 127) acc += ex2[tid + 4];
  acc += __shfl_xor(acc, 1);
  acc += __shfl_xor(acc, 2);
  acc += b3[0];
  float Dv = Dbuf[(((size_t)b * 128 + i) << 7) + px];
  bool m = (i < qlen[b]) && (px < klen[b]);
  float xv = m ? -(acc + Dv) : -100.f;
  float mx = xv;
  #pragma unroll
  for (int o2 = 32; o2; o2 >>= 1) mx = fmaxf(mx, __shfl_xor(mx, o2));
  if ((tid & 63) == 0) redm[wv] = mx;
  __syncthreads();
  mx = fmaxf(fmaxf(fmaxf(redm[0], redm[1]), fmaxf(redm[2], redm[3])),
             fmaxf(fmaxf(redm[4], redm[5]), fmaxf(redm[6], redm[7])));
  float e = __expf(xv - mx);
  float s  = e;
  float de = Dv * e;
  #pragma unroll
  for (int o2 = 32; o2; o2 >>= 1){ s += __shfl_xor(s, o2); de += __shfl_xor(de, o2); }
  if ((tid & 63) == 0){ reds[wv] = s; redd[wv] = de; }
  __syncthreads();
  float s8  = (reds[0] + reds[1]) + (reds[2] + reds[3]) + (reds[4] + reds[5]) + (reds[6] + reds[7]);
  float a = e * 4.0f / s8;
  if (cg == 0) Aout[(((size_t)b * 128 + i) << 7) + px] = a;
  if (tid == 0){
    float d8 = (redd[0] + redd[1]) + (redd[2] + redd[3]) + (redd[4] + redd[5]) + (redd[6] + redd[7]);
    rowsum[b * TT + i] = d8 / s8;
  }
}

// ---------------- dis reduce ----------------
__global__ __launch_bounds__(128) void dis_k(const float* __restrict__ rowsum, float* __restrict__ out){
  int b = blockIdx.x, tid = threadIdx.x;
  float v = rowsum[b * TT + tid];
  #pragma unroll
  for (int o = 32; o; o >>= 1) v += __shfl_xor(v, o);
  __shared__ float red[2];
  if ((tid & 63) == 0) red[tid >> 6] = v;
  __syncthreads();
  if (tid == 0) out[b] = (red[0] + red[1]) * (1.0f / 128.0f);
}

extern "C" void kernel_launch(void* const* d_in, const int* in_sizes, int n_in,
                              void* d_out, int out_size, void* d_ws, size_t ws_size,
                              hipStream_t stream){
  const float* q_seq = (const float*)d_in[0];
  const int*   q_len = (const int*)d_in[1];
  const float* q_R   = (const float*)d_in[2];
  const float* k_seq = (const float*)d_in[3];
  const int*   k_len = (const int*)d_in[4];
  const float* k_R   = (const float*)d_in[5];
  const float* c1w   = (const float*)d_in[6];
  const float* c1b   = (const float*)d_in[7];
  const float* c2w   = (const float*)d_in[8];
  const float* c2b   = (const float*)d_in[9];
  const float* c3w   = (const float*)d_in[10];
  const float* c3b   = (const float*)d_in[11];
  float* out = (float*)d_out;

  char* base = (char*)d_ws;
  size_t off = 0;
  auto take = [&](size_t bytes)->char*{
    char* p = base + off;
    off = (off + bytes + 255) & ~(size_t)255;
    return p;
  };
  float* Dbuf   = (float*)take((size_t)NB * TT * TT * 4);
  float* qq     = (float*)take((size_t)NB * TT * 4);
  float* kkn    = (float*)take((size_t)NB * TT * 4);
  float* rowsum = (float*)take((size_t)NB * TT * 4);
  u32*   inb    = (u32*)  take((size_t)NB * TT * TT * 4);
  u8*    w2p    = (u8*)   take(25 * 1024);
  u16*   w1c    = (u16*)  take(5 * 1024);
  u16*   qb16   = (u16*)  take((size_t)NB * TT * DK * 2);
  u16*   kb16   = (u16*)  take((size_t)NB * TT * DK * 2);
  size_t fixed = off;
  int BCH = 64;
  while (BCH > 1 && fixed + (size_t)BCH * TT * TT * 64 + 1024 > ws_size) BCH >>= 1;
  u8* act1 = (u8*)take((size_t)BCH * TT * TT * 32);
  u8* act2 = (u8*)take((size_t)BCH * TT * TT * 32);

  prep_w_k<<<26, 256, 0, stream>>>(c2w, c1w, w2p, w1c);
  row_norms_k<<<4096, 256, 0, stream>>>(q_seq, k_seq, qq, kkn, qb16, kb16);
  cdist_mfma_k<<<dim3(4, NB), 256, 0, stream>>>(qb16, kb16, qq, kkn, q_len, k_len, q_R, k_R, Dbuf, inb);
  for (int b0 = 0; b0 < NB; b0 += BCH){
    int nb = BCH;
    conv1_mfma_k<<<dim3(16, nb), 512, 0, stream>>>(inb + (size_t)b0 * TT * TT, w1c, c1b, act1);
    conv2_mfma_k<<<dim3(16, nb), 512, 0, stream>>>(act1, w2p, c2b, act2);
    conv3sm_k<<<dim3(TT, nb), 512, 0, stream>>>(act2, c3w, c3b, Dbuf, q_len, k_len, out, rowsum, b0);
  }
  dis_k<<<NB, 128, 0, stream>>>(rowsum, out + (size_t)NB * TT * TT);
}

// Round 14
// 117.820 us; speedup vs baseline: 1.1292x; 1.0662x over previous
//
#include <hip/hip_runtime.h>
#include <hip/hip_bf16.h>
#include <stdint.h>

using u16 = unsigned short;
using u32 = unsigned int;
using u8  = unsigned char;

#define NB 64
#define TT 128
#define DK 768
#define MC 30

typedef float f32x16 __attribute__((ext_vector_type(16)));
typedef __bf16 bf16x8 __attribute__((ext_vector_type(8)));
typedef long long ll;
typedef __attribute__((ext_vector_type(2))) ll ll2;
#if __has_builtin(__builtin_amdgcn_mfma_scale_f32_32x32x64_f8f6f4)
#define HAVE_MXFP8 1
typedef int i32x8 __attribute__((ext_vector_type(8)));
#endif

__device__ inline void unpack2(u32 u, float& lo, float& hi){
  union{u32 i; float f;} a, b; a.i = u << 16; b.i = u & 0xFFFF0000u; lo = a.f; hi = b.f;
}
__device__ inline u16 f2bf(float f){
  union{u32 i; float f;} v; v.f = f;
  u32 r = v.i + 0x7FFFu + ((v.i >> 16) & 1u);
  return (u16)(r >> 16);
}
__device__ inline u32 pack2bf(float a, float b){ return (u32)f2bf(a) | ((u32)f2bf(b) << 16); }

// ---------------- fp8 e4m3fn pack/unpack helpers ----------------
#if __has_builtin(__builtin_amdgcn_cvt_pk_fp8_f32)
template<bool HIW>
__device__ inline u32 pk_fp8(float a, float b, u32 old){
  return (u32)__builtin_amdgcn_cvt_pk_fp8_f32(a, b, (int)old, HIW);
}
#else
__device__ inline u8 f2fp8_1(float f){
  union{float f; u32 u;} v; v.f = f;
  u32 s = (v.u >> 24) & 0x80u;
  u32 abs = v.u & 0x7fffffffu;
  if (abs < 0x3c800000u){
    float sc = fabsf(f) * 512.0f;
    int m = (int)rintf(sc);
    return (u8)(s | (u32)m);
  }
  u32 e8 = abs >> 23; u32 mant = abs & 0x7fffffu;
  u32 m3 = mant >> 20; u32 rest = mant & 0xfffffu;
  u32 rb = (rest > 0x80000u) || (rest == 0x80000u && (m3 & 1u));
  m3 += rb;
  u32 E = e8 - 120u;
  if (m3 == 8u){ m3 = 0u; E += 1u; }
  if (E >= 16u || (E == 15u && m3 == 7u)) return (u8)(s | 0x7Eu);
  return (u8)(s | (E << 3) | m3);
}
template<bool HIW>
__device__ inline u32 pk_fp8(float a, float b, u32 old){
  u32 w = (u32)f2fp8_1(a) | ((u32)f2fp8_1(b) << 8);
  return HIW ? ((old & 0x0000FFFFu) | (w << 16)) : ((old & 0xFFFF0000u) | w);
}
#endif

#if __has_builtin(__builtin_amdgcn_cvt_pk_f32_fp8)
__device__ inline void upk_fp8x4(u32 w, float* x){
  auto a0 = __builtin_amdgcn_cvt_pk_f32_fp8((int)w, false);
  auto a1 = __builtin_amdgcn_cvt_pk_f32_fp8((int)w, true);
  x[0] = a0[0]; x[1] = a0[1]; x[2] = a1[0]; x[3] = a1[1];
}
#else
__device__ inline float fp8_1(u32 byte){
  u32 s = (byte & 0x80u) << 24;
  u32 E = (byte >> 3) & 15u, M = byte & 7u;
  union{u32 u; float f;} v;
  if (E == 0){ v.f = (float)M * (1.0f/512.0f); v.u |= s; }
  else v.u = s | ((E + 120u) << 23) | (M << 20);
  return v.f;
}
__device__ inline void upk_fp8x4(u32 w, float* x){
  x[0] = fp8_1(w & 255u); x[1] = fp8_1((w >> 8) & 255u);
  x[2] = fp8_1((w >> 16) & 255u); x[3] = fp8_1(w >> 24);
}
#endif

// ---------------- weight prep ----------------
// w2p: fp8 [tap][oc32][ic32], intra-page bytes pre-swizzled with ^((oc&7)<<4)
// w1c: bf16 MFMA A-frag table [dy][oc32][k16], k = dx*2 + c (dx>=5 zero), swizzled
__global__ __launch_bounds__(256) void prep_w_k(const float* __restrict__ w2,
    const float* __restrict__ w1, u8* __restrict__ w2p, u16* __restrict__ w1c){
  int bidx = blockIdx.x;
  if (bidx < 25){
    int tap = bidx;
    int i = threadIdx.x;
    int oc = i >> 3, q = i & 7, ic0 = q * 4;
    float v[4];
    #pragma unroll
    for (int j = 0; j < 4; ++j)
      v[j] = (oc < MC && ic0 + j < MC) ? w2[(oc*MC + ic0 + j)*25 + tap] : 0.f;
    u32 w = pk_fp8<false>(v[0], v[1], 0u);
    w = pk_fp8<true>(v[2], v[3], w);
    int lo = ((oc << 5) + (q << 2)) ^ ((oc & 7) << 4);
    *(u32*)(w2p + tap*1024 + lo) = w;
  } else {
    for (int i = threadIdx.x; i < 2560; i += 256){
      int dy = i >> 9; int rem = i & 511; int oc = rem >> 4; int k = rem & 15;
      int dx = k >> 1, c = k & 1;
      float v = (oc < MC && dx < 5) ? w1[(oc*2 + c)*25 + dy*5 + dx] : 0.f;
      int byteoff = dy*1024 + (((oc<<5) + (k<<1)) ^ ((oc&7)<<4));
      *(u16*)((char*)w1c + byteoff) = f2bf(v);
    }
  }
}

// ---------------- kernel 1: row norms + bf16 conversion ----------------
__global__ __launch_bounds__(256) void row_norms_k(const float* __restrict__ q, const float* __restrict__ k,
    float* __restrict__ qq, float* __restrict__ kk,
    u16* __restrict__ qb16, u16* __restrict__ kb16){
  int wave = blockIdx.x * 4 + (threadIdx.x >> 6);
  int lane = threadIdx.x & 63;
  const float* src; float* dst; u16* bdst; int row;
  if (wave < NB * TT) { src = q; dst = qq; bdst = qb16; row = wave; }
  else                { src = k; dst = kk; bdst = kb16; row = wave - NB * TT; }
  const float4* p = (const float4*)(src + (size_t)row * DK + lane * 12);
  u16* ob = bdst + (size_t)row * DK + lane * 12;
  float s = 0.f;
  #pragma unroll
  for (int t = 0; t < 3; ++t){
    float4 v = p[t];
    s += v.x*v.x + v.y*v.y + v.z*v.z + v.w*v.w;
    uint2 st; st.x = pack2bf(v.x, v.y); st.y = pack2bf(v.z, v.w);
    *(uint2*)(ob + t*4) = st;
  }
  #pragma unroll
  for (int o = 32; o; o >>= 1) s += __shfl_xor(s, o);
  if (lane == 0) dst[row] = s;
}

// ---------------- kernel 2: cdist via bf16 MFMA + P + mask ----------------
// inb output: u32 per (b,y,x): lo = bf16(D), hi = bf16(P)
__global__ __launch_bounds__(256) void cdist_mfma_k(
    const u16* __restrict__ Qb16, const u16* __restrict__ Kb16,
    const float* __restrict__ qq, const float* __restrict__ kk,
    const int* __restrict__ qlen, const int* __restrict__ klen,
    const float* __restrict__ qR, const float* __restrict__ kR,
    float* __restrict__ Dout, u32* __restrict__ inb){
  __shared__ __align__(16) char qs[32 * 1536];    // [32 rows][768 k] bf16, swizzled
  __shared__ __align__(16) char ksm[128 * 256];   // [128 cols][128 k] bf16, swizzled
  int rt = blockIdx.x;
  int b  = blockIdx.y;
  int r0 = rt * 32;
  int tid = threadIdx.x;
  const u16* Qg = Qb16 + ((size_t)b * TT + r0) * DK;
  const u16* Kg = Kb16 + (size_t)b * TT * DK;
  for (int idx = tid; idx < 3072; idx += 256){
    int row = idx / 96, ch = idx - row * 96;
    uint4 v = *(const uint4*)(Qg + row * DK + ch * 8);
    *(uint4*)(qs + row * 1536 + ((ch * 16) ^ ((row & 7) << 4))) = v;
  }
  int lane = tid & 63, w = tid >> 6;
  int hi = lane >> 5, l31 = lane & 31;
  int col = w * 32 + l31;
  f32x16 acc;
  #pragma unroll
  for (int r = 0; r < 16; ++r) acc[r] = 0.f;
  for (int kc = 0; kc < DK; kc += 128){
    __syncthreads();
    for (int idx = tid; idx < 2048; idx += 256){
      int c = idx >> 4, j = idx & 15;
      uint4 v = *(const uint4*)(Kg + c * DK + kc + j * 8);
      *(uint4*)(ksm + c * 256 + ((j * 16) ^ ((c & 7) << 4))) = v;
    }
    __syncthreads();
    #pragma unroll
    for (int k8 = 0; k8 < 8; ++k8){
      bf16x8 a  = *(const bf16x8*)(qs  + l31 * 1536 + (((kc + k8*16 + hi*8) * 2) ^ ((l31 & 7) << 4)));
      bf16x8 bv = *(const bf16x8*)(ksm + col * 256  + (((k8*16 + hi*8) * 2) ^ ((col & 7) << 4)));
      acc = __builtin_amdgcn_mfma_f32_32x32x16_bf16(a, bv, acc, 0, 0, 0);
    }
  }
  int ql = qlen[b], kl = klen[b];
  float kkv = kk[b * TT + col];
  float krv = kR[b * TT + col];
  bool cm = col < kl;
  #pragma unroll
  for (int r = 0; r < 16; ++r){
    int row = r0 + (r & 3) + 8 * (r >> 2) + 4 * hi;
    float qqv = qq[b * TT + row];
    float sq = qqv + kkv - 2.f * acc[r];
    float d = sqrtf(fmaxf(sq, 1e-12f));
    bool m = (row < ql) && cm;
    float dm = m ? d : 0.f;
    float pm = m ? fabsf(qR[b * TT + row] - krv) : 0.f;
    Dout[(((size_t)b * TT + row) << 7) + col] = dm;
    inb[(((size_t)b * TT + row) << 7) + col] = pack2bf(dm, pm);
  }
}

// ---------------- conv1: 2ch -> 30ch 5x5 via bf16 MFMA, fp8 out [b][y][x][c32] ----------------
#define C1_ROWW 136
__global__ __launch_bounds__(512, 2) void conv1_mfma_k(const u32* __restrict__ inb,
    const u16* __restrict__ w1c, const float* __restrict__ bias, u8* __restrict__ act1){
  __shared__ u32 ilds[12 * C1_ROWW];
  __shared__ __align__(16) char wlds[5120];
  __shared__ __align__(16) char tr[8 * 4096];
  int yg = blockIdx.x, bb = blockIdx.y;
  int y0 = yg * 8, tid = threadIdx.x;
  {
    const uint4* src = (const uint4*)w1c;
    uint4* dst = (uint4*)wlds;
    for (int i = tid; i < 320; i += 512) dst[i] = src[i];
  }
  for (int i = tid; i < 12 * C1_ROWW; i += 512){
    int r = i / C1_ROWW, xi = i - r * C1_ROWW;
    int gy = y0 - 2 + r, gx = xi - 2;
    u32 v = 0;
    if ((unsigned)gy < 128u && (unsigned)gx < 128u)
      v = inb[(((size_t)bb * 128 + gy) << 7) + gx];
    ilds[r * C1_ROWW + xi] = v;
  }
  __syncthreads();
  int lane = tid & 63, w = tid >> 6;
  int hi = lane >> 5, l31 = lane & 31;
  bf16x8 afr[5];
  #pragma unroll
  for (int dy = 0; dy < 5; ++dy)
    afr[dy] = *(const bf16x8*)(wlds + dy*1024 + (((l31<<5) + (hi<<4)) ^ ((l31&7)<<4)));
  float biasv[16];
  #pragma unroll
  for (int r = 0; r < 16; ++r){
    int oc = (r & 3) + 8*(r >> 2) + 4*hi;
    biasv[r] = (oc < MC) ? bias[oc] : 0.f;
  }
  int wbase = w * 4096;
  #pragma unroll
  for (int t = 0; t < 4; ++t){
    int px = t*32 + l31;
    f32x16 acc;
    #pragma unroll
    for (int r = 0; r < 16; ++r) acc[r] = 0.f;
    #pragma unroll
    for (int dy = 0; dy < 5; ++dy){
      const u32* rp = &ilds[(w + dy)*C1_ROWW + px + hi*4];
      union { u32 uw[4]; bf16x8 v; } ub;
      ub.uw[0] = rp[0]; ub.uw[1] = rp[1]; ub.uw[2] = rp[2]; ub.uw[3] = rp[3];
      acc = __builtin_amdgcn_mfma_f32_32x32x16_bf16(afr[dy], ub.v, acc, 0, 0, 0);
    }
    #pragma unroll
    for (int q = 0; q < 4; ++q){
      float v0 = fmaxf(acc[4*q+0] + biasv[4*q+0], 0.f);
      float v1 = fmaxf(acc[4*q+1] + biasv[4*q+1], 0.f);
      float v2 = fmaxf(acc[4*q+2] + biasv[4*q+2], 0.f);
      float v3 = fmaxf(acc[4*q+3] + biasv[4*q+3], 0.f);
      u32 word = pk_fp8<false>(v0, v1, 0u);
      word = pk_fp8<true>(v2, v3, word);
      int addr = wbase + (((px<<5) + (q<<3) + (hi<<2)) ^ ((px&7)<<3));
      *(u32*)(tr + addr) = word;
    }
  }
  int y = y0 + w;
  #pragma unroll
  for (int p = 0; p < 8; ++p){
    int x = p*16 + (lane >> 2), cg = lane & 3;
    int addr = wbase + (((x<<5) + (cg<<3)) ^ ((x&7)<<3));
    uint2 v = *(const uint2*)(tr + addr);
    *(uint2*)(act1 + ((((size_t)bb*128 + y)*128 + x) << 5) + cg*8) = v;
  }
}

// ---------------- conv2: 30->30 5x5, MX-scaled fp8 MFMA K=64 (unit scales) ----------------
#define C2_IN_ROWB 4224                 // 132 px * 32 B
#define C2_IN_BYTES (12*C2_IN_ROWB)     // 50688
#define C2_W_OFF C2_IN_BYTES
#define C2_SMEM (C2_W_OFF + 25*1024)    // 76288

__global__ __launch_bounds__(512, 4) void conv2_mfma_k(
    const u8* __restrict__ act1, const u8* __restrict__ w2p,
    const float* __restrict__ bias, u8* __restrict__ act2){
  __shared__ __align__(16) char smem[C2_SMEM];
  int o  = blockIdx.x;                    // 0..15
  int yg = ((o & 7) << 1) + (o >> 3);     // XCD-chunked
  int bb = blockIdx.y;
  int y0 = yg * 8;
  int tid = threadIdx.x;
  {
    const uint4* src = (const uint4*)w2p;
    uint4* dst = (uint4*)(smem + C2_W_OFF);
    for (int i = tid; i < 1600; i += 512) dst[i] = src[i];
  }
  for (int i = tid; i < 3168; i += 512){
    int r = i / 264; int t2 = i - r*264; int lx = t2 >> 1; int h = t2 & 1;
    int gy = y0 - 2 + r, gx = lx - 2;
    uint4 v = make_uint4(0,0,0,0);
    if ((unsigned)gy < 128u && (unsigned)gx < 128u)
      v = *(const uint4*)(act1 + ((((size_t)(bb*128 + gy)*128 + gx)) << 5) + (h << 4));
    int boff = ((lx << 5) + (h << 4)) ^ ((lx & 7) << 4);
    *(uint4*)(smem + r*C2_IN_ROWB + boff) = v;
  }
  __syncthreads();
  int lane = tid & 63, w = tid >> 6;
  int hi = lane >> 5, l31 = lane & 31;
  int aBase = C2_W_OFF + (((l31 << 5) + (hi << 4)) ^ ((l31 & 7) << 4));
  f32x16 acc[4];
  #pragma unroll
  for (int t = 0; t < 4; ++t)
    #pragma unroll
    for (int r = 0; r < 16; ++r) acc[t][r] = 0.f;
  #pragma unroll
  for (int dy = 0; dy < 5; ++dy){
    const char* rowp = smem + (w + dy)*C2_IN_ROWB;
    ll2 aw[5];
    #pragma unroll
    for (int dx = 0; dx < 5; ++dx)
      aw[dx] = *(const ll2*)(smem + aBase + (dy*5 + dx)*1024);
#ifdef HAVE_MXFP8
    union U8x { struct { ll2 lo, hi; } p; i32x8 v; };
    U8x a01, a23, a4z;
    ll2 zz; zz.x = 0; zz.y = 0;
    a01.p.lo = aw[0]; a01.p.hi = aw[1];
    a23.p.lo = aw[2]; a23.p.hi = aw[3];
    a4z.p.lo = aw[4]; a4z.p.hi = zz;
    #pragma unroll
    for (int t = 0; t < 4; ++t){
      int pxb = t*32 + l31;
      ll2 bl[5];
      #pragma unroll
      for (int dx = 0; dx < 5; ++dx){
        int px2 = pxb + dx;
        int boff = ((px2 << 5) + (hi << 4)) ^ ((px2 & 7) << 4);
        bl[dx] = *(const ll2*)(rowp + boff);
      }
      U8x b01, b23, b4d;
      b01.p.lo = bl[0]; b01.p.hi = bl[1];
      b23.p.lo = bl[2]; b23.p.hi = bl[3];
      b4d.p.lo = bl[4]; b4d.p.hi = bl[4];   // A upper half is zero -> B value irrelevant
      acc[t] = __builtin_amdgcn_mfma_scale_f32_32x32x64_f8f6f4(
                 a01.v, b01.v, acc[t], 0, 0, 0, 0x7F7F7F7F, 0, 0x7F7F7F7F);
      acc[t] = __builtin_amdgcn_mfma_scale_f32_32x32x64_f8f6f4(
                 a23.v, b23.v, acc[t], 0, 0, 0, 0x7F7F7F7F, 0, 0x7F7F7F7F);
      acc[t] = __builtin_amdgcn_mfma_scale_f32_32x32x64_f8f6f4(
                 a4z.v, b4d.v, acc[t], 0, 0, 0, 0x7F7F7F7F, 0, 0x7F7F7F7F);
    }
#else
    #pragma unroll
    for (int dx = 0; dx < 5; ++dx){
      ll2 a = aw[dx];
      #pragma unroll
      for (int t = 0; t < 4; ++t){
        int px2 = t*32 + l31 + dx;
        int boff = ((px2 << 5) + (hi << 4)) ^ ((px2 & 7) << 4);
        ll2 b = *(const ll2*)(rowp + boff);
        acc[t] = __builtin_amdgcn_mfma_f32_32x32x16_fp8_fp8(a.x, b.x, acc[t], 0, 0, 0);
        acc[t] = __builtin_amdgcn_mfma_f32_32x32x16_fp8_fp8(a.y, b.y, acc[t], 0, 0, 0);
      }
    }
#endif
  }
  float biasv[16];
  #pragma unroll
  for (int r = 0; r < 16; ++r){
    int oc = (r & 3) + 8*(r >> 2) + 4*hi;
    biasv[r] = (oc < MC) ? bias[oc] : 0.f;
  }
  __syncthreads();
  // transpose via LDS (per-wave 4KB region; 2-way-max swizzle)
  int wbase = w * 8192;
  #pragma unroll
  for (int t = 0; t < 4; ++t){
    int px = t*32 + l31;
    #pragma unroll
    for (int q = 0; q < 4; ++q){
      float v0 = fmaxf(acc[t][4*q+0] + biasv[4*q+0], 0.f);
      float v1 = fmaxf(acc[t][4*q+1] + biasv[4*q+1], 0.f);
      float v2 = fmaxf(acc[t][4*q+2] + biasv[4*q+2], 0.f);
      float v3 = fmaxf(acc[t][4*q+3] + biasv[4*q+3], 0.f);
      u32 word = pk_fp8<false>(v0, v1, 0u);
      word = pk_fp8<true>(v2, v3, word);
      int addr = wbase + (((px<<5) + (q<<3) + (hi<<2)) ^ (((px>>2)&3)<<3));
      *(u32*)(smem + addr) = word;
    }
  }
  int y = y0 + w;
  #pragma unroll
  for (int p = 0; p < 8; ++p){
    int x = p*16 + (lane >> 2), cg = lane & 3;
    int addr = wbase + (((x<<5) + (cg<<3)) ^ (((x>>2)&3)<<3));
    uint2 v = *(const uint2*)(smem + addr);
    *(uint2*)(act2 + ((((size_t)bb*128 + y)*128 + x) << 5) + cg*8) = v;
  }
}

// ---------------- conv3 + mask + row softmax + A write + row D*A (+ XCD-chunked i) ----------------
__global__ __launch_bounds__(512) void conv3sm_k(const u8* __restrict__ act2,
    const float* __restrict__ w3, const float* __restrict__ b3, const float* __restrict__ Dbuf,
    const int* __restrict__ qlen, const int* __restrict__ klen,
    float* __restrict__ Aout, float* __restrict__ rowsum, int b0){
  __shared__ float wlds[9][32];
  __shared__ float ex0[512], ex2[512];
  __shared__ float redm[8], reds[8], redd[8];
  int o  = blockIdx.x;                    // 0..127
  int i  = ((o & 7) << 4) + (o >> 3);     // XCD-chunked
  int bb = blockIdx.y;
  int b  = b0 + bb;
  int tid = threadIdx.x;
  for (int idx = tid; idx < 288; idx += 512){
    int tap = idx >> 5, c = idx & 31;
    wlds[tap][c] = (c < MC) ? w3[c * 9 + tap] : 0.f;
  }
  __syncthreads();
  int px = tid >> 2, cg = tid & 3, wv = tid >> 6;
  float T0 = 0.f, T1 = 0.f, T2 = 0.f;
  #pragma unroll
  for (int dy = 0; dy < 3; ++dy){
    int gy = i - 1 + dy;
    uint2 v = make_uint2(0, 0);
    if ((unsigned)gy < 128u)
      v = *(const uint2*)(act2 + ((((size_t)bb*128 + gy)*128 + px) << 5) + cg*8);
    float x[8];
    upk_fp8x4(v.x, x);
    upk_fp8x4(v.y, x + 4);
    const float* w0p = &wlds[dy*3 + 0][cg*8];
    const float* w1p = &wlds[dy*3 + 1][cg*8];
    const float* w2q = &wlds[dy*3 + 2][cg*8];
    #pragma unroll
    for (int c = 0; c < 8; ++c){
      T0 = fmaf(x[c], w0p[c], T0);
      T1 = fmaf(x[c], w1p[c], T1);
      T2 = fmaf(x[c], w2q[c], T2);
    }
  }
  ex0[tid] = T0; ex2[tid] = T2;
  __syncthreads();
  float acc = T1;
  if (px > 0)   acc += ex0[tid - 4];
  if (px < 127) acc += ex2[tid + 4];
  acc += __shfl_xor(acc, 1);
  acc += __shfl_xor(acc, 2);
  acc += b3[0];
  float Dv = Dbuf[(((size_t)b * 128 + i) << 7) + px];
  bool m = (i < qlen[b]) && (px < klen[b]);
  float xv = m ? -(acc + Dv) : -100.f;
  float mx = xv;
  #pragma unroll
  for (int o2 = 32; o2; o2 >>= 1) mx = fmaxf(mx, __shfl_xor(mx, o2));
  if ((tid & 63) == 0) redm[wv] = mx;
  __syncthreads();
  mx = fmaxf(fmaxf(fmaxf(redm[0], redm[1]), fmaxf(redm[2], redm[3])),
             fmaxf(fmaxf(redm[4], redm[5]), fmaxf(redm[6], redm[7])));
  float e = __expf(xv - mx);
  float s  = e;
  float de = Dv * e;
  #pragma unroll
  for (int o2 = 32; o2; o2 >>= 1){ s += __shfl_xor(s, o2); de += __shfl_xor(de, o2); }
  if ((tid & 63) == 0){ reds[wv] = s; redd[wv] = de; }
  __syncthreads();
  float s8  = (reds[0] + reds[1]) + (reds[2] + reds[3]) + (reds[4] + reds[5]) + (reds[6] + reds[7]);
  float a = e * 4.0f / s8;
  if (cg == 0) Aout[(((size_t)b * 128 + i) << 7) + px] = a;
  if (tid == 0){
    float d8 = (redd[0] + redd[1]) + (redd[2] + redd[3]) + (redd[4] + redd[5]) + (redd[6] + redd[7]);
    rowsum[b * TT + i] = d8 / s8;
  }
}

// ---------------- dis reduce ----------------
__global__ __launch_bounds__(128) void dis_k(const float* __restrict__ rowsum, float* __restrict__ out){
  int b = blockIdx.x, tid = threadIdx.x;
  float v = rowsum[b * TT + tid];
  #pragma unroll
  for (int o = 32; o; o >>= 1) v += __shfl_xor(v, o);
  __shared__ float red[2];
  if ((tid & 63) == 0) red[tid >> 6] = v;
  __syncthreads();
  if (tid == 0) out[b] = (red[0] + red[1]) * (1.0f / 128.0f);
}

extern "C" void kernel_launch(void* const* d_in, const int* in_sizes, int n_in,
                              void* d_out, int out_size, void* d_ws, size_t ws_size,
                              hipStream_t stream){
  const float* q_seq = (const float*)d_in[0];
  const int*   q_len = (const int*)d_in[1];
  const float* q_R   = (const float*)d_in[2];
  const float* k_seq = (const float*)d_in[3];
  const int*   k_len = (const int*)d_in[4];
  const float* k_R   = (const float*)d_in[5];
  const float* c1w   = (const float*)d_in[6];
  const float* c1b   = (const float*)d_in[7];
  const float* c2w   = (const float*)d_in[8];
  const float* c2b   = (const float*)d_in[9];
  const float* c3w   = (const float*)d_in[10];
  const float* c3b   = (const float*)d_in[11];
  float* out = (float*)d_out;

  char* base = (char*)d_ws;
  size_t off = 0;
  auto take = [&](size_t bytes)->char*{
    char* p = base + off;
    off = (off + bytes + 255) & ~(size_t)255;
    return p;
  };
  float* Dbuf   = (float*)take((size_t)NB * TT * TT * 4);
  float* qq     = (float*)take((size_t)NB * TT * 4);
  float* kkn    = (float*)take((size_t)NB * TT * 4);
  float* rowsum = (float*)take((size_t)NB * TT * 4);
  u32*   inb    = (u32*)  take((size_t)NB * TT * TT * 4);
  u8*    w2p    = (u8*)   take(25 * 1024);
  u16*   w1c    = (u16*)  take(5 * 1024);
  u16*   qb16   = (u16*)  take((size_t)NB * TT * DK * 2);
  u16*   kb16   = (u16*)  take((size_t)NB * TT * DK * 2);
  size_t fixed = off;
  int BCH = 64;
  while (BCH > 1 && fixed + (size_t)BCH * TT * TT * 64 + 1024 > ws_size) BCH >>= 1;
  u8* act1 = (u8*)take((size_t)BCH * TT * TT * 32);
  u8* act2 = (u8*)take((size_t)BCH * TT * TT * 32);

  prep_w_k<<<26, 256, 0, stream>>>(c2w, c1w, w2p, w1c);
  row_norms_k<<<4096, 256, 0, stream>>>(q_seq, k_seq, qq, kkn, qb16, kb16);
  cdist_mfma_k<<<dim3(4, NB), 256, 0, stream>>>(qb16, kb16, qq, kkn, q_len, k_len, q_R, k_R, Dbuf, inb);
  for (int b0 = 0; b0 < NB; b0 += BCH){
    int nb = BCH;
    conv1_mfma_k<<<dim3(16, nb), 512, 0, stream>>>(inb + (size_t)b0 * TT * TT, w1c, c1b, act1);
    conv2_mfma_k<<<dim3(16, nb), 512, 0, stream>>>(act1, w2p, c2b, act2);
    conv3sm_k<<<dim3(TT, nb), 512, 0, stream>>>(act2, c3w, c3b, Dbuf, q_len, k_len, out, rowsum, b0);
  }
  dis_k<<<NB, 128, 0, stream>>>(rowsum, out + (size_t)NB * TT * TT);
}

// Round 15
// 109.514 us; speedup vs baseline: 1.2148x; 1.0758x over previous
//
#include <hip/hip_runtime.h>
#include <hip/hip_bf16.h>
#include <stdint.h>

using u16 = unsigned short;
using u32 = unsigned int;
using u8  = unsigned char;

#define NB 64
#define TT 128
#define DK 768
#define MC 30

typedef float f32x16 __attribute__((ext_vector_type(16)));
typedef __bf16 bf16x8 __attribute__((ext_vector_type(8)));
typedef long long ll;
typedef __attribute__((ext_vector_type(2))) ll ll2;
#if __has_builtin(__builtin_amdgcn_mfma_scale_f32_32x32x64_f8f6f4)
#define HAVE_MXFP8 1
typedef int i32x8 __attribute__((ext_vector_type(8)));
#endif

__device__ inline void unpack2(u32 u, float& lo, float& hi){
  union{u32 i; float f;} a, b; a.i = u << 16; b.i = u & 0xFFFF0000u; lo = a.f; hi = b.f;
}
__device__ inline u16 f2bf(float f){
  union{u32 i; float f;} v; v.f = f;
  u32 r = v.i + 0x7FFFu + ((v.i >> 16) & 1u);
  return (u16)(r >> 16);
}
__device__ inline u32 pack2bf(float a, float b){ return (u32)f2bf(a) | ((u32)f2bf(b) << 16); }

// ---------------- fp8 e4m3fn pack/unpack helpers ----------------
#if __has_builtin(__builtin_amdgcn_cvt_pk_fp8_f32)
template<bool HIW>
__device__ inline u32 pk_fp8(float a, float b, u32 old){
  return (u32)__builtin_amdgcn_cvt_pk_fp8_f32(a, b, (int)old, HIW);
}
#else
__device__ inline u8 f2fp8_1(float f){
  union{float f; u32 u;} v; v.f = f;
  u32 s = (v.u >> 24) & 0x80u;
  u32 abs = v.u & 0x7fffffffu;
  if (abs < 0x3c800000u){
    float sc = fabsf(f) * 512.0f;
    int m = (int)rintf(sc);
    return (u8)(s | (u32)m);
  }
  u32 e8 = abs >> 23; u32 mant = abs & 0x7fffffu;
  u32 m3 = mant >> 20; u32 rest = mant & 0xfffffu;
  u32 rb = (rest > 0x80000u) || (rest == 0x80000u && (m3 & 1u));
  m3 += rb;
  u32 E = e8 - 120u;
  if (m3 == 8u){ m3 = 0u; E += 1u; }
  if (E >= 16u || (E == 15u && m3 == 7u)) return (u8)(s | 0x7Eu);
  return (u8)(s | (E << 3) | m3);
}
template<bool HIW>
__device__ inline u32 pk_fp8(float a, float b, u32 old){
  u32 w = (u32)f2fp8_1(a) | ((u32)f2fp8_1(b) << 8);
  return HIW ? ((old & 0x0000FFFFu) | (w << 16)) : ((old & 0xFFFF0000u) | w);
}
#endif

#if __has_builtin(__builtin_amdgcn_cvt_pk_f32_fp8)
__device__ inline void upk_fp8x4(u32 w, float* x){
  auto a0 = __builtin_amdgcn_cvt_pk_f32_fp8((int)w, false);
  auto a1 = __builtin_amdgcn_cvt_pk_f32_fp8((int)w, true);
  x[0] = a0[0]; x[1] = a0[1]; x[2] = a1[0]; x[3] = a1[1];
}
#else
__device__ inline float fp8_1(u32 byte){
  u32 s = (byte & 0x80u) << 24;
  u32 E = (byte >> 3) & 15u, M = byte & 7u;
  union{u32 u; float f;} v;
  if (E == 0){ v.f = (float)M * (1.0f/512.0f); v.u |= s; }
  else v.u = s | ((E + 120u) << 23) | (M << 20);
  return v.f;
}
__device__ inline void upk_fp8x4(u32 w, float* x){
  x[0] = fp8_1(w & 255u); x[1] = fp8_1((w >> 8) & 255u);
  x[2] = fp8_1((w >> 16) & 255u); x[3] = fp8_1(w >> 24);
}
#endif

// ---------------- weight prep ----------------
// w2p: fp8 [tap][oc32][ic32], intra-page bytes pre-swizzled with ^((oc&7)<<4)
// w1c: bf16 MFMA A-frag table [dy][oc32][k16], k = dx*2 + c (dx>=5 zero), swizzled
__global__ __launch_bounds__(256) void prep_w_k(const float* __restrict__ w2,
    const float* __restrict__ w1, u8* __restrict__ w2p, u16* __restrict__ w1c){
  int bidx = blockIdx.x;
  if (bidx < 25){
    int tap = bidx;
    int i = threadIdx.x;
    int oc = i >> 3, q = i & 7, ic0 = q * 4;
    float v[4];
    #pragma unroll
    for (int j = 0; j < 4; ++j)
      v[j] = (oc < MC && ic0 + j < MC) ? w2[(oc*MC + ic0 + j)*25 + tap] : 0.f;
    u32 w = pk_fp8<false>(v[0], v[1], 0u);
    w = pk_fp8<true>(v[2], v[3], w);
    int lo = ((oc << 5) + (q << 2)) ^ ((oc & 7) << 4);
    *(u32*)(w2p + tap*1024 + lo) = w;
  } else {
    for (int i = threadIdx.x; i < 2560; i += 256){
      int dy = i >> 9; int rem = i & 511; int oc = rem >> 4; int k = rem & 15;
      int dx = k >> 1, c = k & 1;
      float v = (oc < MC && dx < 5) ? w1[(oc*2 + c)*25 + dy*5 + dx] : 0.f;
      int byteoff = dy*1024 + (((oc<<5) + (k<<1)) ^ ((oc&7)<<4));
      *(u16*)((char*)w1c + byteoff) = f2bf(v);
    }
  }
}

// ---------------- kernel 1: row norms + bf16 conversion ----------------
__global__ __launch_bounds__(256) void row_norms_k(const float* __restrict__ q, const float* __restrict__ k,
    float* __restrict__ qq, float* __restrict__ kk,
    u16* __restrict__ qb16, u16* __restrict__ kb16){
  int wave = blockIdx.x * 4 + (threadIdx.x >> 6);
  int lane = threadIdx.x & 63;
  const float* src; float* dst; u16* bdst; int row;
  if (wave < NB * TT) { src = q; dst = qq; bdst = qb16; row = wave; }
  else                { src = k; dst = kk; bdst = kb16; row = wave - NB * TT; }
  const float4* p = (const float4*)(src + (size_t)row * DK + lane * 12);
  u16* ob = bdst + (size_t)row * DK + lane * 12;
  float s = 0.f;
  #pragma unroll
  for (int t = 0; t < 3; ++t){
    float4 v = p[t];
    s += v.x*v.x + v.y*v.y + v.z*v.z + v.w*v.w;
    uint2 st; st.x = pack2bf(v.x, v.y); st.y = pack2bf(v.z, v.w);
    *(uint2*)(ob + t*4) = st;
  }
  #pragma unroll
  for (int o = 32; o; o >>= 1) s += __shfl_xor(s, o);
  if (lane == 0) dst[row] = s;
}

// ---------------- kernel 2: cdist via bf16 MFMA + P + mask ----------------
// inb output: u32 per (b,y,x): lo = bf16(D), hi = bf16(P)
__global__ __launch_bounds__(256) void cdist_mfma_k(
    const u16* __restrict__ Qb16, const u16* __restrict__ Kb16,
    const float* __restrict__ qq, const float* __restrict__ kk,
    const int* __restrict__ qlen, const int* __restrict__ klen,
    const float* __restrict__ qR, const float* __restrict__ kR,
    float* __restrict__ Dout, u32* __restrict__ inb){
  __shared__ __align__(16) char qs[32 * 1536];    // [32 rows][768 k] bf16, swizzled
  __shared__ __align__(16) char ksm[128 * 256];   // [128 cols][128 k] bf16, swizzled
  int rt = blockIdx.x;
  int b  = blockIdx.y;
  int r0 = rt * 32;
  int tid = threadIdx.x;
  const u16* Qg = Qb16 + ((size_t)b * TT + r0) * DK;
  const u16* Kg = Kb16 + (size_t)b * TT * DK;
  for (int idx = tid; idx < 3072; idx += 256){
    int row = idx / 96, ch = idx - row * 96;
    uint4 v = *(const uint4*)(Qg + row * DK + ch * 8);
    *(uint4*)(qs + row * 1536 + ((ch * 16) ^ ((row & 7) << 4))) = v;
  }
  int lane = tid & 63, w = tid >> 6;
  int hi = lane >> 5, l31 = lane & 31;
  int col = w * 32 + l31;
  f32x16 acc;
  #pragma unroll
  for (int r = 0; r < 16; ++r) acc[r] = 0.f;
  for (int kc = 0; kc < DK; kc += 128){
    __syncthreads();
    for (int idx = tid; idx < 2048; idx += 256){
      int c = idx >> 4, j = idx & 15;
      uint4 v = *(const uint4*)(Kg + c * DK + kc + j * 8);
      *(uint4*)(ksm + c * 256 + ((j * 16) ^ ((c & 7) << 4))) = v;
    }
    __syncthreads();
    #pragma unroll
    for (int k8 = 0; k8 < 8; ++k8){
      bf16x8 a  = *(const bf16x8*)(qs  + l31 * 1536 + (((kc + k8*16 + hi*8) * 2) ^ ((l31 & 7) << 4)));
      bf16x8 bv = *(const bf16x8*)(ksm + col * 256  + (((k8*16 + hi*8) * 2) ^ ((col & 7) << 4)));
      acc = __builtin_amdgcn_mfma_f32_32x32x16_bf16(a, bv, acc, 0, 0, 0);
    }
  }
  int ql = qlen[b], kl = klen[b];
  float kkv = kk[b * TT + col];
  float krv = kR[b * TT + col];
  bool cm = col < kl;
  #pragma unroll
  for (int r = 0; r < 16; ++r){
    int row = r0 + (r & 3) + 8 * (r >> 2) + 4 * hi;
    float qqv = qq[b * TT + row];
    float sq = qqv + kkv - 2.f * acc[r];
    float d = sqrtf(fmaxf(sq, 1e-12f));
    bool m = (row < ql) && cm;
    float dm = m ? d : 0.f;
    float pm = m ? fabsf(qR[b * TT + row] - krv) : 0.f;
    Dout[(((size_t)b * TT + row) << 7) + col] = dm;
    inb[(((size_t)b * TT + row) << 7) + col] = pack2bf(dm, pm);
  }
}

// ---------------- fused conv1+conv2 ----------------
// conv1 (2ch->30ch 5x5, bf16 MFMA) computed in-block into LDS, then
// conv2 (30->30 5x5, MX-scaled fp8 MFMA K=64, unit scales, weights from global/L1)
#define C1_ROWW 136
#define C2_IN_ROWB 4224                 // 132 px * 32 B
#define F_INB_BYTES (16*C1_ROWW*4)      // 8704
#define F_C2_OFF F_INB_BYTES
#define F_SMEM (F_INB_BYTES + 12*C2_IN_ROWB)   // 59392

__global__ __launch_bounds__(512, 4) void conv12_mfma_k(
    const u32* __restrict__ inb, const u8* __restrict__ w2p, const u16* __restrict__ w1c,
    const float* __restrict__ b1, const float* __restrict__ b2, u8* __restrict__ act2){
  __shared__ __align__(16) char smem[F_SMEM];
  u32* ilds = (u32*)smem;               // [16][136] bf16x2 (D,P)
  char* c2in = smem + F_C2_OFF;         // [12][132 px][ic32] fp8, swizzled
  int o  = blockIdx.x;                    // 0..15
  int yg = ((o & 7) << 1) + (o >> 3);     // XCD-chunked
  int bb = blockIdx.y;
  int y0 = yg * 8;
  int tid = threadIdx.x;
  // stage inb rows y0-4 .. y0+11 (gx = xi-2)
  for (int i = tid; i < 16*C1_ROWW; i += 512){
    int r = i / C1_ROWW, xi = i - r * C1_ROWW;
    int gy = y0 - 4 + r, gx = xi - 2;
    u32 v = 0;
    if ((unsigned)gy < 128u && (unsigned)gx < 128u)
      v = inb[(((size_t)bb * 128 + gy) << 7) + gx];
    ilds[r * C1_ROWW + xi] = v;
  }
  // zero pad columns lx in {0,1,130,131} of c2in
  for (int i = tid; i < 96; i += 512){
    int r = i >> 3; int rem = i & 7; int ci = rem >> 1; int h = rem & 1;
    int lx = (ci < 2) ? ci : (128 + ci);
    int addr = r*C2_IN_ROWB + (((lx << 5) + (h << 4)) ^ ((lx & 7) << 4));
    *(uint4*)(c2in + addr) = make_uint4(0,0,0,0);
  }
  int lane = tid & 63, w = tid >> 6;
  int hi = lane >> 5, l31 = lane & 31;
  int aSwz = ((l31 << 5) + (hi << 4)) ^ ((l31 & 7) << 4);
  // conv1 weight A-frags from global (5KB, L1-hot)
  bf16x8 afr[5];
  #pragma unroll
  for (int dy = 0; dy < 5; ++dy)
    afr[dy] = *(const bf16x8*)((const char*)w1c + dy*1024 + aSwz);
  float b1v[16];
  #pragma unroll
  for (int r = 0; r < 16; ++r){
    int oc = (r & 3) + 8*(r >> 2) + 4*hi;
    b1v[r] = (oc < MC) ? b1[oc] : 0.f;
  }
  __syncthreads();
  // ---- conv1 phase: rows idx = w (all waves) and idx = 8+w (waves 0..3); gy = y0-2+idx
  for (int rep = 0; rep < 2; ++rep){
    if (rep == 1 && w >= 4) break;
    int idx = (rep == 0) ? w : (8 + w);
    int gy = y0 - 2 + idx;
    bool oob = (unsigned)gy >= 128u;
    #pragma unroll
    for (int t = 0; t < 4; ++t){
      int px = t*32 + l31;
      u32 words[4];
      if (!oob){
        f32x16 acc;
        #pragma unroll
        for (int r = 0; r < 16; ++r) acc[r] = 0.f;
        #pragma unroll
        for (int dy = 0; dy < 5; ++dy){
          const u32* rp = &ilds[(idx + dy)*C1_ROWW + px + hi*4];
          union { u32 uw[4]; bf16x8 v; } ub;
          ub.uw[0] = rp[0]; ub.uw[1] = rp[1]; ub.uw[2] = rp[2]; ub.uw[3] = rp[3];
          acc = __builtin_amdgcn_mfma_f32_32x32x16_bf16(afr[dy], ub.v, acc, 0, 0, 0);
        }
        #pragma unroll
        for (int q = 0; q < 4; ++q){
          u32 word = pk_fp8<false>(fmaxf(acc[4*q+0]+b1v[4*q+0], 0.f),
                                   fmaxf(acc[4*q+1]+b1v[4*q+1], 0.f), 0u);
          word = pk_fp8<true>(fmaxf(acc[4*q+2]+b1v[4*q+2], 0.f),
                              fmaxf(acc[4*q+3]+b1v[4*q+3], 0.f), word);
          words[q] = word;
        }
      } else {
        words[0] = words[1] = words[2] = words[3] = 0u;
      }
      int lx = px + 2;
      #pragma unroll
      for (int q = 0; q < 4; ++q){
        int ic = q*8 + hi*4;   // oc quad position within ic32 (bit4 = half selector)
        int addr = idx*C2_IN_ROWB + (((lx << 5) + ic) ^ ((lx & 7) << 4));
        *(u32*)(c2in + addr) = words[q];
      }
    }
  }
  __syncthreads();
  // ---- conv2 phase (MX-scaled fp8, K=64, unit scales), A-frags from global
  f32x16 acc[4];
  #pragma unroll
  for (int t = 0; t < 4; ++t)
    #pragma unroll
    for (int r = 0; r < 16; ++r) acc[t][r] = 0.f;
  #pragma unroll
  for (int dy = 0; dy < 5; ++dy){
    const char* rowp = c2in + (w + dy)*C2_IN_ROWB;
    ll2 aw[5];
    #pragma unroll
    for (int dx = 0; dx < 5; ++dx)
      aw[dx] = *(const ll2*)(w2p + (dy*5 + dx)*1024 + aSwz);
#ifdef HAVE_MXFP8
    union U8x { struct { ll2 lo, hi; } p; i32x8 v; };
    U8x a01, a23, a4z;
    ll2 zz; zz.x = 0; zz.y = 0;
    a01.p.lo = aw[0]; a01.p.hi = aw[1];
    a23.p.lo = aw[2]; a23.p.hi = aw[3];
    a4z.p.lo = aw[4]; a4z.p.hi = zz;
    #pragma unroll
    for (int t = 0; t < 4; ++t){
      int pxb = t*32 + l31;
      ll2 bl[5];
      #pragma unroll
      for (int dx = 0; dx < 5; ++dx){
        int px2 = pxb + dx;
        int boff = ((px2 << 5) + (hi << 4)) ^ ((px2 & 7) << 4);
        bl[dx] = *(const ll2*)(rowp + boff);
      }
      U8x b01, b23, b4d;
      b01.p.lo = bl[0]; b01.p.hi = bl[1];
      b23.p.lo = bl[2]; b23.p.hi = bl[3];
      b4d.p.lo = bl[4]; b4d.p.hi = bl[4];   // A upper half is zero
      acc[t] = __builtin_amdgcn_mfma_scale_f32_32x32x64_f8f6f4(
                 a01.v, b01.v, acc[t], 0, 0, 0, 0x7F7F7F7F, 0, 0x7F7F7F7F);
      acc[t] = __builtin_amdgcn_mfma_scale_f32_32x32x64_f8f6f4(
                 a23.v, b23.v, acc[t], 0, 0, 0, 0x7F7F7F7F, 0, 0x7F7F7F7F);
      acc[t] = __builtin_amdgcn_mfma_scale_f32_32x32x64_f8f6f4(
                 a4z.v, b4d.v, acc[t], 0, 0, 0, 0x7F7F7F7F, 0, 0x7F7F7F7F);
    }
#else
    #pragma unroll
    for (int dx = 0; dx < 5; ++dx){
      ll2 a = aw[dx];
      #pragma unroll
      for (int t = 0; t < 4; ++t){
        int px2 = t*32 + l31 + dx;
        int boff = ((px2 << 5) + (hi << 4)) ^ ((px2 & 7) << 4);
        ll2 b = *(const ll2*)(rowp + boff);
        acc[t] = __builtin_amdgcn_mfma_f32_32x32x16_fp8_fp8(a.x, b.x, acc[t], 0, 0, 0);
        acc[t] = __builtin_amdgcn_mfma_f32_32x32x16_fp8_fp8(a.y, b.y, acc[t], 0, 0, 0);
      }
    }
#endif
  }
  float b2v[16];
  #pragma unroll
  for (int r = 0; r < 16; ++r){
    int oc = (r & 3) + 8*(r >> 2) + 4*hi;
    b2v[r] = (oc < MC) ? b2[oc] : 0.f;
  }
  __syncthreads();   // all LDS reads done before transpose overwrite
  // transpose via LDS (per-wave 4KB region inside dead c2in area)
  int wbase = w * 4096;
  #pragma unroll
  for (int t = 0; t < 4; ++t){
    int px = t*32 + l31;
    #pragma unroll
    for (int q = 0; q < 4; ++q){
      float v0 = fmaxf(acc[t][4*q+0] + b2v[4*q+0], 0.f);
      float v1 = fmaxf(acc[t][4*q+1] + b2v[4*q+1], 0.f);
      float v2 = fmaxf(acc[t][4*q+2] + b2v[4*q+2], 0.f);
      float v3 = fmaxf(acc[t][4*q+3] + b2v[4*q+3], 0.f);
      u32 word = pk_fp8<false>(v0, v1, 0u);
      word = pk_fp8<true>(v2, v3, word);
      int addr = wbase + (((px<<5) + (q<<3) + (hi<<2)) ^ (((px>>2)&3)<<3));
      *(u32*)(c2in + addr) = word;
    }
  }
  int y = y0 + w;
  #pragma unroll
  for (int p = 0; p < 8; ++p){
    int x = p*16 + (lane >> 2), cg = lane & 3;
    int addr = wbase + (((x<<5) + (cg<<3)) ^ (((x>>2)&3)<<3));
    uint2 v = *(const uint2*)(c2in + addr);
    *(uint2*)(act2 + ((((size_t)bb*128 + y)*128 + x) << 5) + cg*8) = v;
  }
}

// ---------------- conv3 + mask + row softmax + A write + row D*A (+ XCD-chunked i) ----------------
__global__ __launch_bounds__(512) void conv3sm_k(const u8* __restrict__ act2,
    const float* __restrict__ w3, const float* __restrict__ b3, const float* __restrict__ Dbuf,
    const int* __restrict__ qlen, const int* __restrict__ klen,
    float* __restrict__ Aout, float* __restrict__ rowsum, int b0){
  __shared__ float wlds[9][32];
  __shared__ float ex0[512], ex2[512];
  __shared__ float redm[8], reds[8], redd[8];
  int o  = blockIdx.x;                    // 0..127
  int i  = ((o & 7) << 4) + (o >> 3);     // XCD-chunked
  int bb = blockIdx.y;
  int b  = b0 + bb;
  int tid = threadIdx.x;
  for (int idx = tid; idx < 288; idx += 512){
    int tap = idx >> 5, c = idx & 31;
    wlds[tap][c] = (c < MC) ? w3[c * 9 + tap] : 0.f;
  }
  __syncthreads();
  int px = tid >> 2, cg = tid & 3, wv = tid >> 6;
  float T0 = 0.f, T1 = 0.f, T2 = 0.f;
  #pragma unroll
  for (int dy = 0; dy < 3; ++dy){
    int gy = i - 1 + dy;
    uint2 v = make_uint2(0, 0);
    if ((unsigned)gy < 128u)
      v = *(const uint2*)(act2 + ((((size_t)bb*128 + gy)*128 + px) << 5) + cg*8);
    float x[8];
    upk_fp8x4(v.x, x);
    upk_fp8x4(v.y, x + 4);
    const float* w0p = &wlds[dy*3 + 0][cg*8];
    const float* w1p = &wlds[dy*3 + 1][cg*8];
    const float* w2q = &wlds[dy*3 + 2][cg*8];
    #pragma unroll
    for (int c = 0; c < 8; ++c){
      T0 = fmaf(x[c], w0p[c], T0);
      T1 = fmaf(x[c], w1p[c], T1);
      T2 = fmaf(x[c], w2q[c], T2);
    }
  }
  ex0[tid] = T0; ex2[tid] = T2;
  __syncthreads();
  float acc = T1;
  if (px > 0)   acc += ex0[tid - 4];
  if (px < 127) acc += ex2[tid + 4];
  acc += __shfl_xor(acc, 1);
  acc += __shfl_xor(acc, 2);
  acc += b3[0];
  float Dv = Dbuf[(((size_t)b * 128 + i) << 7) + px];
  bool m = (i < qlen[b]) && (px < klen[b]);
  float xv = m ? -(acc + Dv) : -100.f;
  float mx = xv;
  #pragma unroll
  for (int o2 = 32; o2; o2 >>= 1) mx = fmaxf(mx, __shfl_xor(mx, o2));
  if ((tid & 63) == 0) redm[wv] = mx;
  __syncthreads();
  mx = fmaxf(fmaxf(fmaxf(redm[0], redm[1]), fmaxf(redm[2], redm[3])),
             fmaxf(fmaxf(redm[4], redm[5]), fmaxf(redm[6], redm[7])));
  float e = __expf(xv - mx);
  float s  = e;
  float de = Dv * e;
  #pragma unroll
  for (int o2 = 32; o2; o2 >>= 1){ s += __shfl_xor(s, o2); de += __shfl_xor(de, o2); }
  if ((tid & 63) == 0){ reds[wv] = s; redd[wv] = de; }
  __syncthreads();
  float s8  = (reds[0] + reds[1]) + (reds[2] + reds[3]) + (reds[4] + reds[5]) + (reds[6] + reds[7]);
  float a = e * 4.0f / s8;
  if (cg == 0) Aout[(((size_t)b * 128 + i) << 7) + px] = a;
  if (tid == 0){
    float d8 = (redd[0] + redd[1]) + (redd[2] + redd[3]) + (redd[4] + redd[5]) + (redd[6] + redd[7]);
    rowsum[b * TT + i] = d8 / s8;
  }
}

// ---------------- dis reduce ----------------
__global__ __launch_bounds__(128) void dis_k(const float* __restrict__ rowsum, float* __restrict__ out){
  int b = blockIdx.x, tid = threadIdx.x;
  float v = rowsum[b * TT + tid];
  #pragma unroll
  for (int o = 32; o; o >>= 1) v += __shfl_xor(v, o);
  __shared__ float red[2];
  if ((tid & 63) == 0) red[tid >> 6] = v;
  __syncthreads();
  if (tid == 0) out[b] = (red[0] + red[1]) * (1.0f / 128.0f);
}

extern "C" void kernel_launch(void* const* d_in, const int* in_sizes, int n_in,
                              void* d_out, int out_size, void* d_ws, size_t ws_size,
                              hipStream_t stream){
  const float* q_seq = (const float*)d_in[0];
  const int*   q_len = (const int*)d_in[1];
  const float* q_R   = (const float*)d_in[2];
  const float* k_seq = (const float*)d_in[3];
  const int*   k_len = (const int*)d_in[4];
  const float* k_R   = (const float*)d_in[5];
  const float* c1w   = (const float*)d_in[6];
  const float* c1b   = (const float*)d_in[7];
  const float* c2w   = (const float*)d_in[8];
  const float* c2b   = (const float*)d_in[9];
  const float* c3w   = (const float*)d_in[10];
  const float* c3b   = (const float*)d_in[11];
  float* out = (float*)d_out;

  char* base = (char*)d_ws;
  size_t off = 0;
  auto take = [&](size_t bytes)->char*{
    char* p = base + off;
    off = (off + bytes + 255) & ~(size_t)255;
    return p;
  };
  float* Dbuf   = (float*)take((size_t)NB * TT * TT * 4);
  float* qq     = (float*)take((size_t)NB * TT * 4);
  float* kkn    = (float*)take((size_t)NB * TT * 4);
  float* rowsum = (float*)take((size_t)NB * TT * 4);
  u32*   inb    = (u32*)  take((size_t)NB * TT * TT * 4);
  u8*    w2p    = (u8*)   take(25 * 1024);
  u16*   w1c    = (u16*)  take(5 * 1024);
  u16*   qb16   = (u16*)  take((size_t)NB * TT * DK * 2);
  u16*   kb16   = (u16*)  take((size_t)NB * TT * DK * 2);
  size_t fixed = off;
  int BCH = 64;
  while (BCH > 1 && fixed + (size_t)BCH * TT * TT * 32 + 1024 > ws_size) BCH >>= 1;
  u8* act2 = (u8*)take((size_t)BCH * TT * TT * 32);

  prep_w_k<<<26, 256, 0, stream>>>(c2w, c1w, w2p, w1c);
  row_norms_k<<<4096, 256, 0, stream>>>(q_seq, k_seq, qq, kkn, qb16, kb16);
  cdist_mfma_k<<<dim3(4, NB), 256, 0, stream>>>(qb16, kb16, qq, kkn, q_len, k_len, q_R, k_R, Dbuf, inb);
  for (int b0 = 0; b0 < NB; b0 += BCH){
    int nb = BCH;
    conv12_mfma_k<<<dim3(16, nb), 512, 0, stream>>>(inb + (size_t)b0 * TT * TT, w2p, w1c, c1b, c2b, act2);
    conv3sm_k<<<dim3(TT, nb), 512, 0, stream>>>(act2, c3w, c3b, Dbuf, q_len, k_len, out, rowsum, b0);
  }
  dis_k<<<NB, 128, 0, stream>>>(rowsum, out + (size_t)NB * TT * TT);
}

// Round 16
// 104.453 us; speedup vs baseline: 1.2737x; 1.0485x over previous
//
#include <hip/hip_runtime.h>
#include <hip/hip_bf16.h>
#include <stdint.h>

using u16 = unsigned short;
using u32 = unsigned int;
using u8  = unsigned char;

#define NB 64
#define TT 128
#define DK 768
#define MC 30

typedef float f32x16 __attribute__((ext_vector_type(16)));
typedef __bf16 bf16x8 __attribute__((ext_vector_type(8)));
typedef long long ll;
typedef __attribute__((ext_vector_type(2))) ll ll2;
#if __has_builtin(__builtin_amdgcn_mfma_scale_f32_32x32x64_f8f6f4)
#define HAVE_MXFP8 1
typedef int i32x8 __attribute__((ext_vector_type(8)));
#endif
#if __has_builtin(__builtin_amdgcn_global_load_lds)
#define HAVE_GLDS 1
#endif

__device__ inline void unpack2(u32 u, float& lo, float& hi){
  union{u32 i; float f;} a, b; a.i = u << 16; b.i = u & 0xFFFF0000u; lo = a.f; hi = b.f;
}
__device__ inline u16 f2bf(float f){
  union{u32 i; float f;} v; v.f = f;
  u32 r = v.i + 0x7FFFu + ((v.i >> 16) & 1u);
  return (u16)(r >> 16);
}
__device__ inline u32 pack2bf(float a, float b){ return (u32)f2bf(a) | ((u32)f2bf(b) << 16); }

// ---------------- fp8 e4m3fn pack/unpack helpers ----------------
#if __has_builtin(__builtin_amdgcn_cvt_pk_fp8_f32)
template<bool HIW>
__device__ inline u32 pk_fp8(float a, float b, u32 old){
  return (u32)__builtin_amdgcn_cvt_pk_fp8_f32(a, b, (int)old, HIW);
}
#else
__device__ inline u8 f2fp8_1(float f){
  union{float f; u32 u;} v; v.f = f;
  u32 s = (v.u >> 24) & 0x80u;
  u32 abs = v.u & 0x7fffffffu;
  if (abs < 0x3c800000u){
    float sc = fabsf(f) * 512.0f;
    int m = (int)rintf(sc);
    return (u8)(s | (u32)m);
  }
  u32 e8 = abs >> 23; u32 mant = abs & 0x7fffffu;
  u32 m3 = mant >> 20; u32 rest = mant & 0xfffffu;
  u32 rb = (rest > 0x80000u) || (rest == 0x80000u && (m3 & 1u));
  m3 += rb;
  u32 E = e8 - 120u;
  if (m3 == 8u){ m3 = 0u; E += 1u; }
  if (E >= 16u || (E == 15u && m3 == 7u)) return (u8)(s | 0x7Eu);
  return (u8)(s | (E << 3) | m3);
}
template<bool HIW>
__device__ inline u32 pk_fp8(float a, float b, u32 old){
  u32 w = (u32)f2fp8_1(a) | ((u32)f2fp8_1(b) << 8);
  return HIW ? ((old & 0x0000FFFFu) | (w << 16)) : ((old & 0xFFFF0000u) | w);
}
#endif

#if __has_builtin(__builtin_amdgcn_cvt_pk_f32_fp8)
__device__ inline void upk_fp8x4(u32 w, float* x){
  auto a0 = __builtin_amdgcn_cvt_pk_f32_fp8((int)w, false);
  auto a1 = __builtin_amdgcn_cvt_pk_f32_fp8((int)w, true);
  x[0] = a0[0]; x[1] = a0[1]; x[2] = a1[0]; x[3] = a1[1];
}
#else
__device__ inline float fp8_1(u32 byte){
  u32 s = (byte & 0x80u) << 24;
  u32 E = (byte >> 3) & 15u, M = byte & 7u;
  union{u32 u; float f;} v;
  if (E == 0){ v.f = (float)M * (1.0f/512.0f); v.u |= s; }
  else v.u = s | ((E + 120u) << 23) | (M << 20);
  return v.f;
}
__device__ inline void upk_fp8x4(u32 w, float* x){
  x[0] = fp8_1(w & 255u); x[1] = fp8_1((w >> 8) & 255u);
  x[2] = fp8_1((w >> 16) & 255u); x[3] = fp8_1(w >> 24);
}
#endif

// ---------------- weight prep ----------------
// w2p: fp8 [tap][oc32][ic32], intra-page bytes pre-swizzled with ^((oc&7)<<4)
// w1c: bf16 MFMA A-frag table [dy][oc32][k16], k = dx*2 + c (dx>=5 zero), swizzled
__global__ __launch_bounds__(256) void prep_w_k(const float* __restrict__ w2,
    const float* __restrict__ w1, u8* __restrict__ w2p, u16* __restrict__ w1c){
  int bidx = blockIdx.x;
  if (bidx < 25){
    int tap = bidx;
    int i = threadIdx.x;
    int oc = i >> 3, q = i & 7, ic0 = q * 4;
    float v[4];
    #pragma unroll
    for (int j = 0; j < 4; ++j)
      v[j] = (oc < MC && ic0 + j < MC) ? w2[(oc*MC + ic0 + j)*25 + tap] : 0.f;
    u32 w = pk_fp8<false>(v[0], v[1], 0u);
    w = pk_fp8<true>(v[2], v[3], w);
    int lo = ((oc << 5) + (q << 2)) ^ ((oc & 7) << 4);
    *(u32*)(w2p + tap*1024 + lo) = w;
  } else {
    for (int i = threadIdx.x; i < 2560; i += 256){
      int dy = i >> 9; int rem = i & 511; int oc = rem >> 4; int k = rem & 15;
      int dx = k >> 1, c = k & 1;
      float v = (oc < MC && dx < 5) ? w1[(oc*2 + c)*25 + dy*5 + dx] : 0.f;
      int byteoff = dy*1024 + (((oc<<5) + (k<<1)) ^ ((oc&7)<<4));
      *(u16*)((char*)w1c + byteoff) = f2bf(v);
    }
  }
}

// ---------------- kernel 1: row norms + bf16 conversion (PRE-SWIZZLED output) ----------------
// qb16/kb16 rows of 1536B hold 16B granules permuted by ^((row&7)<<4) so cdist
// can stage with a pure linear copy and read with the same XOR.
__global__ __launch_bounds__(256) void row_norms_k(const float* __restrict__ q, const float* __restrict__ k,
    float* __restrict__ qq, float* __restrict__ kk,
    u16* __restrict__ qb16, u16* __restrict__ kb16){
  int wave = blockIdx.x * 4 + (threadIdx.x >> 6);
  int lane = threadIdx.x & 63;
  const float* src; float* dst; u16* bdst; int row;
  if (wave < NB * TT) { src = q; dst = qq; bdst = qb16; row = wave; }
  else                { src = k; dst = kk; bdst = kb16; row = wave - NB * TT; }
  const float4* p = (const float4*)(src + (size_t)row * DK);
  char* ob = (char*)(bdst + (size_t)row * DK);
  int key = (row & 7) << 4;
  float s = 0.f;
  {
    float4 a = p[2*lane], b2 = p[2*lane + 1];
    s += a.x*a.x + a.y*a.y + a.z*a.z + a.w*a.w;
    s += b2.x*b2.x + b2.y*b2.y + b2.z*b2.z + b2.w*b2.w;
    uint4 st;
    st.x = pack2bf(a.x, a.y);  st.y = pack2bf(a.z, a.w);
    st.z = pack2bf(b2.x, b2.y); st.w = pack2bf(b2.z, b2.w);
    *(uint4*)(ob + ((lane << 4) ^ key)) = st;
  }
  if (lane < 32){
    int g = 64 + lane;
    float4 a = p[2*g], b2 = p[2*g + 1];
    s += a.x*a.x + a.y*a.y + a.z*a.z + a.w*a.w;
    s += b2.x*b2.x + b2.y*b2.y + b2.z*b2.z + b2.w*b2.w;
    uint4 st;
    st.x = pack2bf(a.x, a.y);  st.y = pack2bf(a.z, a.w);
    st.z = pack2bf(b2.x, b2.y); st.w = pack2bf(b2.z, b2.w);
    *(uint4*)(ob + ((g << 4) ^ key)) = st;
  }
  #pragma unroll
  for (int o = 32; o; o >>= 1) s += __shfl_xor(s, o);
  if (lane == 0) dst[row] = s;
}

// ---------------- kernel 2: cdist via bf16 MFMA, async linear staging ----------------
// inb output: u32 per (b,y,x): lo = bf16(D), hi = bf16(P)
__global__ __launch_bounds__(256) void cdist_mfma_k(
    const u16* __restrict__ Qb16, const u16* __restrict__ Kb16,
    const float* __restrict__ qq, const float* __restrict__ kk,
    const int* __restrict__ qlen, const int* __restrict__ klen,
    const float* __restrict__ qR, const float* __restrict__ kR,
    float* __restrict__ Dout, u32* __restrict__ inb){
  __shared__ __align__(16) char qs[32 * 1536];    // [32 rows][768 k] bf16, swizzled content
  __shared__ __align__(16) char ksm[128 * 256];   // [128 cols][128 k] bf16, swizzled content
  int rt = blockIdx.x;
  int b  = blockIdx.y;
  int r0 = rt * 32;
  int tid = threadIdx.x;
  int lane = tid & 63, w = tid >> 6;
  int hi = lane >> 5, l31 = lane & 31;
  const char* Qg = (const char*)(Qb16 + ((size_t)b * TT + r0) * DK);
  const char* Kg = (const char*)(Kb16 + (size_t)b * TT * DK);
  // stage Q: pure linear 48KB copy (global already pre-swizzled)
#ifdef HAVE_GLDS
  #pragma unroll
  for (int i = 0; i < 12; ++i){
    int gb = (i*4 + w) << 6;
    __builtin_amdgcn_global_load_lds((const u32*)(Qg + ((gb + lane) << 4)),
                                     (u32*)(qs + (gb << 4)), 16, 0, 0);
  }
#else
  for (int idx = tid; idx < 3072; idx += 256)
    *(uint4*)(qs + idx*16) = *(const uint4*)(Qg + idx*16);
#endif
  int col = w * 32 + l31;
  f32x16 acc;
  #pragma unroll
  for (int r = 0; r < 16; ++r) acc[r] = 0.f;
  for (int kc = 0; kc < DK; kc += 128){
    __syncthreads();
    // stage K chunk: linear within each row's 256B chunk slice
#ifdef HAVE_GLDS
    const char* Ks = Kg + kc*2;
    #pragma unroll
    for (int i = 0; i < 8; ++i){
      int gb = (i*4 + w) << 6;
      int g = gb + lane;
      __builtin_amdgcn_global_load_lds((const u32*)(Ks + (g >> 4)*1536 + ((g & 15) << 4)),
                                       (u32*)(ksm + (gb << 4)), 16, 0, 0);
    }
#else
    for (int idx = tid; idx < 2048; idx += 256){
      int c = idx >> 4, j = idx & 15;
      *(uint4*)(ksm + idx*16) = *(const uint4*)(Kg + c*1536 + kc*2 + j*16);
    }
#endif
    __syncthreads();
    #pragma unroll
    for (int k8 = 0; k8 < 8; ++k8){
      bf16x8 a  = *(const bf16x8*)(qs  + l31 * 1536 + (((kc + k8*16 + hi*8) * 2) ^ ((l31 & 7) << 4)));
      bf16x8 bv = *(const bf16x8*)(ksm + col * 256  + (((k8*16 + hi*8) * 2) ^ ((col & 7) << 4)));
      acc = __builtin_amdgcn_mfma_f32_32x32x16_bf16(a, bv, acc, 0, 0, 0);
    }
  }
  int ql = qlen[b], kl = klen[b];
  float kkv = kk[b * TT + col];
  float krv = kR[b * TT + col];
  bool cm = col < kl;
  #pragma unroll
  for (int r = 0; r < 16; ++r){
    int row = r0 + (r & 3) + 8 * (r >> 2) + 4 * hi;
    float qqv = qq[b * TT + row];
    float sq = qqv + kkv - 2.f * acc[r];
    float d = sqrtf(fmaxf(sq, 1e-12f));
    bool m = (row < ql) && cm;
    float dm = m ? d : 0.f;
    float pm = m ? fabsf(qR[b * TT + row] - krv) : 0.f;
    Dout[(((size_t)b * TT + row) << 7) + col] = dm;
    inb[(((size_t)b * TT + row) << 7) + col] = pack2bf(dm, pm);
  }
}

// ---------------- fused conv1+conv2 ----------------
#define C1_ROWW 136
#define C2_IN_ROWB 4224                 // 132 px * 32 B
#define F_INB_BYTES (16*C1_ROWW*4)      // 8704
#define F_C2_OFF F_INB_BYTES
#define F_SMEM (F_INB_BYTES + 12*C2_IN_ROWB)   // 59392

__global__ __launch_bounds__(512, 4) void conv12_mfma_k(
    const u32* __restrict__ inb, const u8* __restrict__ w2p, const u16* __restrict__ w1c,
    const float* __restrict__ b1, const float* __restrict__ b2, u8* __restrict__ act2){
  __shared__ __align__(16) char smem[F_SMEM];
  u32* ilds = (u32*)smem;               // [16][136] bf16x2 (D,P)
  char* c2in = smem + F_C2_OFF;         // [12][132 px][ic32] fp8, swizzled
  int o  = blockIdx.x;                    // 0..15
  int yg = ((o & 7) << 1) + (o >> 3);     // XCD-chunked
  int bb = blockIdx.y;
  int y0 = yg * 8;
  int tid = threadIdx.x;
  for (int i = tid; i < 16*C1_ROWW; i += 512){
    int r = i / C1_ROWW, xi = i - r * C1_ROWW;
    int gy = y0 - 4 + r, gx = xi - 2;
    u32 v = 0;
    if ((unsigned)gy < 128u && (unsigned)gx < 128u)
      v = inb[(((size_t)bb * 128 + gy) << 7) + gx];
    ilds[r * C1_ROWW + xi] = v;
  }
  for (int i = tid; i < 96; i += 512){
    int r = i >> 3; int rem = i & 7; int ci = rem >> 1; int h = rem & 1;
    int lx = (ci < 2) ? ci : (128 + ci);
    int addr = r*C2_IN_ROWB + (((lx << 5) + (h << 4)) ^ ((lx & 7) << 4));
    *(uint4*)(c2in + addr) = make_uint4(0,0,0,0);
  }
  int lane = tid & 63, w = tid >> 6;
  int hi = lane >> 5, l31 = lane & 31;
  int aSwz = ((l31 << 5) + (hi << 4)) ^ ((l31 & 7) << 4);
  bf16x8 afr[5];
  #pragma unroll
  for (int dy = 0; dy < 5; ++dy)
    afr[dy] = *(const bf16x8*)((const char*)w1c + dy*1024 + aSwz);
  float b1v[16];
  #pragma unroll
  for (int r = 0; r < 16; ++r){
    int oc = (r & 3) + 8*(r >> 2) + 4*hi;
    b1v[r] = (oc < MC) ? b1[oc] : 0.f;
  }
  __syncthreads();
  // ---- conv1 phase
  for (int rep = 0; rep < 2; ++rep){
    if (rep == 1 && w >= 4) break;
    int idx = (rep == 0) ? w : (8 + w);
    int gy = y0 - 2 + idx;
    bool oob = (unsigned)gy >= 128u;
    #pragma unroll
    for (int t = 0; t < 4; ++t){
      int px = t*32 + l31;
      u32 words[4];
      if (!oob){
        f32x16 acc;
        #pragma unroll
        for (int r = 0; r < 16; ++r) acc[r] = 0.f;
        #pragma unroll
        for (int dy = 0; dy < 5; ++dy){
          const u32* rp = &ilds[(idx + dy)*C1_ROWW + px + hi*4];
          union { u32 uw[4]; bf16x8 v; } ub;
          ub.uw[0] = rp[0]; ub.uw[1] = rp[1]; ub.uw[2] = rp[2]; ub.uw[3] = rp[3];
          acc = __builtin_amdgcn_mfma_f32_32x32x16_bf16(afr[dy], ub.v, acc, 0, 0, 0);
        }
        #pragma unroll
        for (int q = 0; q < 4; ++q){
          u32 word = pk_fp8<false>(fmaxf(acc[4*q+0]+b1v[4*q+0], 0.f),
                                   fmaxf(acc[4*q+1]+b1v[4*q+1], 0.f), 0u);
          word = pk_fp8<true>(fmaxf(acc[4*q+2]+b1v[4*q+2], 0.f),
                              fmaxf(acc[4*q+3]+b1v[4*q+3], 0.f), word);
          words[q] = word;
        }
      } else {
        words[0] = words[1] = words[2] = words[3] = 0u;
      }
      int lx = px + 2;
      #pragma unroll
      for (int q = 0; q < 4; ++q){
        int ic = q*8 + hi*4;
        int addr = idx*C2_IN_ROWB + (((lx << 5) + ic) ^ ((lx & 7) << 4));
        *(u32*)(c2in + addr) = words[q];
      }
    }
  }
  __syncthreads();
  // ---- conv2 phase (MX-scaled fp8, K=64, unit scales), A-frags from global
  f32x16 acc[4];
  #pragma unroll
  for (int t = 0; t < 4; ++t)
    #pragma unroll
    for (int r = 0; r < 16; ++r) acc[t][r] = 0.f;
  #pragma unroll
  for (int dy = 0; dy < 5; ++dy){
    const char* rowp = c2in + (w + dy)*C2_IN_ROWB;
    ll2 aw[5];
    #pragma unroll
    for (int dx = 0; dx < 5; ++dx)
      aw[dx] = *(const ll2*)(w2p + (dy*5 + dx)*1024 + aSwz);
#ifdef HAVE_MXFP8
    union U8x { struct { ll2 lo, hi; } p; i32x8 v; };
    U8x a01, a23, a4z;
    ll2 zz; zz.x = 0; zz.y = 0;
    a01.p.lo = aw[0]; a01.p.hi = aw[1];
    a23.p.lo = aw[2]; a23.p.hi = aw[3];
    a4z.p.lo = aw[4]; a4z.p.hi = zz;
    #pragma unroll
    for (int t = 0; t < 4; ++t){
      int pxb = t*32 + l31;
      ll2 bl[5];
      #pragma unroll
      for (int dx = 0; dx < 5; ++dx){
        int px2 = pxb + dx;
        int boff = ((px2 << 5) + (hi << 4)) ^ ((px2 & 7) << 4);
        bl[dx] = *(const ll2*)(rowp + boff);
      }
      U8x b01, b23, b4d;
      b01.p.lo = bl[0]; b01.p.hi = bl[1];
      b23.p.lo = bl[2]; b23.p.hi = bl[3];
      b4d.p.lo = bl[4]; b4d.p.hi = bl[4];
      acc[t] = __builtin_amdgcn_mfma_scale_f32_32x32x64_f8f6f4(
                 a01.v, b01.v, acc[t], 0, 0, 0, 0x7F7F7F7F, 0, 0x7F7F7F7F);
      acc[t] = __builtin_amdgcn_mfma_scale_f32_32x32x64_f8f6f4(
                 a23.v, b23.v, acc[t], 0, 0, 0, 0x7F7F7F7F, 0, 0x7F7F7F7F);
      acc[t] = __builtin_amdgcn_mfma_scale_f32_32x32x64_f8f6f4(
                 a4z.v, b4d.v, acc[t], 0, 0, 0, 0x7F7F7F7F, 0, 0x7F7F7F7F);
    }
#else
    #pragma unroll
    for (int dx = 0; dx < 5; ++dx){
      ll2 a = aw[dx];
      #pragma unroll
      for (int t = 0; t < 4; ++t){
        int px2 = t*32 + l31 + dx;
        int boff = ((px2 << 5) + (hi << 4)) ^ ((px2 & 7) << 4);
        ll2 b = *(const ll2*)(rowp + boff);
        acc[t] = __builtin_amdgcn_mfma_f32_32x32x16_fp8_fp8(a.x, b.x, acc[t], 0, 0, 0);
        acc[t] = __builtin_amdgcn_mfma_f32_32x32x16_fp8_fp8(a.y, b.y, acc[t], 0, 0, 0);
      }
    }
#endif
  }
  float b2v[16];
  #pragma unroll
  for (int r = 0; r < 16; ++r){
    int oc = (r & 3) + 8*(r >> 2) + 4*hi;
    b2v[r] = (oc < MC) ? b2[oc] : 0.f;
  }
  __syncthreads();
  int wbase = w * 4096;
  #pragma unroll
  for (int t = 0; t < 4; ++t){
    int px = t*32 + l31;
    #pragma unroll
    for (int q = 0; q < 4; ++q){
      float v0 = fmaxf(acc[t][4*q+0] + b2v[4*q+0], 0.f);
      float v1 = fmaxf(acc[t][4*q+1] + b2v[4*q+1], 0.f);
      float v2 = fmaxf(acc[t][4*q+2] + b2v[4*q+2], 0.f);
      float v3 = fmaxf(acc[t][4*q+3] + b2v[4*q+3], 0.f);
      u32 word = pk_fp8<false>(v0, v1, 0u);
      word = pk_fp8<true>(v2, v3, word);
      int addr = wbase + (((px<<5) + (q<<3) + (hi<<2)) ^ (((px>>2)&3)<<3));
      *(u32*)(c2in + addr) = word;
    }
  }
  int y = y0 + w;
  #pragma unroll
  for (int p = 0; p < 8; ++p){
    int x = p*16 + (lane >> 2), cg = lane & 3;
    int addr = wbase + (((x<<5) + (cg<<3)) ^ (((x>>2)&3)<<3));
    uint2 v = *(const uint2*)(c2in + addr);
    *(uint2*)(act2 + ((((size_t)bb*128 + y)*128 + x) << 5) + cg*8) = v;
  }
}

// ---------------- conv3 + mask + row softmax + A write + row D*A (+ XCD-chunked i) ----------------
__global__ __launch_bounds__(512) void conv3sm_k(const u8* __restrict__ act2,
    const float* __restrict__ w3, const float* __restrict__ b3, const float* __restrict__ Dbuf,
    const int* __restrict__ qlen, const int* __restrict__ klen,
    float* __restrict__ Aout, float* __restrict__ rowsum, int b0){
  __shared__ float wlds[9][32];
  __shared__ float ex0[512], ex2[512];
  __shared__ float redm[8], reds[8], redd[8];
  int o  = blockIdx.x;                    // 0..127
  int i  = ((o & 7) << 4) + (o >> 3);     // XCD-chunked
  int bb = blockIdx.y;
  int b  = b0 + bb;
  int tid = threadIdx.x;
  for (int idx = tid; idx < 288; idx += 512){
    int tap = idx >> 5, c = idx & 31;
    wlds[tap][c] = (c < MC) ? w3[c * 9 + tap] : 0.f;
  }
  __syncthreads();
  int px = tid >> 2, cg = tid & 3, wv = tid >> 6;
  float T0 = 0.f, T1 = 0.f, T2 = 0.f;
  #pragma unroll
  for (int dy = 0; dy < 3; ++dy){
    int gy = i - 1 + dy;
    uint2 v = make_uint2(0, 0);
    if ((unsigned)gy < 128u)
      v = *(const uint2*)(act2 + ((((size_t)bb*128 + gy)*128 + px) << 5) + cg*8);
    float x[8];
    upk_fp8x4(v.x, x);
    upk_fp8x4(v.y, x + 4);
    const float* w0p = &wlds[dy*3 + 0][cg*8];
    const float* w1p = &wlds[dy*3 + 1][cg*8];
    const float* w2q = &wlds[dy*3 + 2][cg*8];
    #pragma unroll
    for (int c = 0; c < 8; ++c){
      T0 = fmaf(x[c], w0p[c], T0);
      T1 = fmaf(x[c], w1p[c], T1);
      T2 = fmaf(x[c], w2q[c], T2);
    }
  }
  ex0[tid] = T0; ex2[tid] = T2;
  __syncthreads();
  float acc = T1;
  if (px > 0)   acc += ex0[tid - 4];
  if (px < 127) acc += ex2[tid + 4];
  acc += __shfl_xor(acc, 1);
  acc += __shfl_xor(acc, 2);
  acc += b3[0];
  float Dv = Dbuf[(((size_t)b * 128 + i) << 7) + px];
  bool m = (i < qlen[b]) && (px < klen[b]);
  float xv = m ? -(acc + Dv) : -100.f;
  float mx = xv;
  #pragma unroll
  for (int o2 = 32; o2; o2 >>= 1) mx = fmaxf(mx, __shfl_xor(mx, o2));
  if ((tid & 63) == 0) redm[wv] = mx;
  __syncthreads();
  mx = fmaxf(fmaxf(fmaxf(redm[0], redm[1]), fmaxf(redm[2], redm[3])),
             fmaxf(fmaxf(redm[4], redm[5]), fmaxf(redm[6], redm[7])));
  float e = __expf(xv - mx);
  float s  = e;
  float de = Dv * e;
  #pragma unroll
  for (int o2 = 32; o2; o2 >>= 1){ s += __shfl_xor(s, o2); de += __shfl_xor(de, o2); }
  if ((tid & 63) == 0){ reds[wv] = s; redd[wv] = de; }
  __syncthreads();
  float s8  = (reds[0] + reds[1]) + (reds[2] + reds[3]) + (reds[4] + reds[5]) + (reds[6] + reds[7]);
  float a = e * 4.0f / s8;
  if (cg == 0) Aout[(((size_t)b * 128 + i) << 7) + px] = a;
  if (tid == 0){
    float d8 = (redd[0] + redd[1]) + (redd[2] + redd[3]) + (redd[4] + redd[5]) + (redd[6] + redd[7]);
    rowsum[b * TT + i] = d8 / s8;
  }
}

// ---------------- dis reduce ----------------
__global__ __launch_bounds__(128) void dis_k(const float* __restrict__ rowsum, float* __restrict__ out){
  int b = blockIdx.x, tid = threadIdx.x;
  float v = rowsum[b * TT + tid];
  #pragma unroll
  for (int o = 32; o; o >>= 1) v += __shfl_xor(v, o);
  __shared__ float red[2];
  if ((tid & 63) == 0) red[tid >> 6] = v;
  __syncthreads();
  if (tid == 0) out[b] = (red[0] + red[1]) * (1.0f / 128.0f);
}

extern "C" void kernel_launch(void* const* d_in, const int* in_sizes, int n_in,
                              void* d_out, int out_size, void* d_ws, size_t ws_size,
                              hipStream_t stream){
  const float* q_seq = (const float*)d_in[0];
  const int*   q_len = (const int*)d_in[1];
  const float* q_R   = (const float*)d_in[2];
  const float* k_seq = (const float*)d_in[3];
  const int*   k_len = (const int*)d_in[4];
  const float* k_R   = (const float*)d_in[5];
  const float* c1w   = (const float*)d_in[6];
  const float* c1b   = (const float*)d_in[7];
  const float* c2w   = (const float*)d_in[8];
  const float* c2b   = (const float*)d_in[9];
  const float* c3w   = (const float*)d_in[10];
  const float* c3b   = (const float*)d_in[11];
  float* out = (float*)d_out;

  char* base = (char*)d_ws;
  size_t off = 0;
  auto take = [&](size_t bytes)->char*{
    char* p = base + off;
    off = (off + bytes + 255) & ~(size_t)255;
    return p;
  };
  float* Dbuf   = (float*)take((size_t)NB * TT * TT * 4);
  float* qq     = (float*)take((size_t)NB * TT * 4);
  float* kkn    = (float*)take((size_t)NB * TT * 4);
  float* rowsum = (float*)take((size_t)NB * TT * 4);
  u32*   inb    = (u32*)  take((size_t)NB * TT * TT * 4);
  u8*    w2p    = (u8*)   take(25 * 1024);
  u16*   w1c    = (u16*)  take(5 * 1024);
  u16*   qb16   = (u16*)  take((size_t)NB * TT * DK * 2);
  u16*   kb16   = (u16*)  take((size_t)NB * TT * DK * 2);
  size_t fixed = off;
  int BCH = 64;
  while (BCH > 1 && fixed + (size_t)BCH * TT * TT * 32 + 1024 > ws_size) BCH >>= 1;
  u8* act2 = (u8*)take((size_t)BCH * TT * TT * 32);

  prep_w_k<<<26, 256, 0, stream>>>(c2w, c1w, w2p, w1c);
  row_norms_k<<<4096, 256, 0, stream>>>(q_seq, k_seq, qq, kkn, qb16, kb16);
  cdist_mfma_k<<<dim3(4, NB), 256, 0, stream>>>(qb16, kb16, qq, kkn, q_len, k_len, q_R, k_R, Dbuf, inb);
  for (int b0 = 0; b0 < NB; b0 += BCH){
    int nb = BCH;
    conv12_mfma_k<<<dim3(16, nb), 512, 0, stream>>>(inb + (size_t)b0 * TT * TT, w2p, w1c, c1b, c2b, act2);
    conv3sm_k<<<dim3(TT, nb), 512, 0, stream>>>(act2, c3w, c3b, Dbuf, q_len, k_len, out, rowsum, b0);
  }
  dis_k<<<NB, 128, 0, stream>>>(rowsum, out + (size_t)NB * TT * TT);
}

// Round 17
// 98.528 us; speedup vs baseline: 1.3503x; 1.0601x over previous
//
#include <hip/hip_runtime.h>
#include <hip/hip_bf16.h>
#include <stdint.h>

using u16 = unsigned short;
using u32 = unsigned int;
using u8  = unsigned char;

#define NB 64
#define TT 128
#define DK 768
#define MC 30

typedef float f32x16 __attribute__((ext_vector_type(16)));
typedef __bf16 bf16x8 __attribute__((ext_vector_type(8)));
typedef long long ll;
typedef __attribute__((ext_vector_type(2))) ll ll2;
#if __has_builtin(__builtin_amdgcn_mfma_scale_f32_32x32x64_f8f6f4)
#define HAVE_MXFP8 1
typedef int i32x8 __attribute__((ext_vector_type(8)));
#endif
#if __has_builtin(__builtin_amdgcn_global_load_lds)
#define HAVE_GLDS 1
#endif

__device__ inline void unpack2(u32 u, float& lo, float& hi){
  union{u32 i; float f;} a, b; a.i = u << 16; b.i = u & 0xFFFF0000u; lo = a.f; hi = b.f;
}
__device__ inline u16 f2bf(float f){
  union{u32 i; float f;} v; v.f = f;
  u32 r = v.i + 0x7FFFu + ((v.i >> 16) & 1u);
  return (u16)(r >> 16);
}
__device__ inline u32 pack2bf(float a, float b){ return (u32)f2bf(a) | ((u32)f2bf(b) << 16); }

// ---------------- fp8 e4m3fn pack/unpack helpers ----------------
#if __has_builtin(__builtin_amdgcn_cvt_pk_fp8_f32)
template<bool HIW>
__device__ inline u32 pk_fp8(float a, float b, u32 old){
  return (u32)__builtin_amdgcn_cvt_pk_fp8_f32(a, b, (int)old, HIW);
}
#else
__device__ inline u8 f2fp8_1(float f){
  union{float f; u32 u;} v; v.f = f;
  u32 s = (v.u >> 24) & 0x80u;
  u32 abs = v.u & 0x7fffffffu;
  if (abs < 0x3c800000u){
    float sc = fabsf(f) * 512.0f;
    int m = (int)rintf(sc);
    return (u8)(s | (u32)m);
  }
  u32 e8 = abs >> 23; u32 mant = abs & 0x7fffffu;
  u32 m3 = mant >> 20; u32 rest = mant & 0xfffffu;
  u32 rb = (rest > 0x80000u) || (rest == 0x80000u && (m3 & 1u));
  m3 += rb;
  u32 E = e8 - 120u;
  if (m3 == 8u){ m3 = 0u; E += 1u; }
  if (E >= 16u || (E == 15u && m3 == 7u)) return (u8)(s | 0x7Eu);
  return (u8)(s | (E << 3) | m3);
}
template<bool HIW>
__device__ inline u32 pk_fp8(float a, float b, u32 old){
  u32 w = (u32)f2fp8_1(a) | ((u32)f2fp8_1(b) << 8);
  return HIW ? ((old & 0x0000FFFFu) | (w << 16)) : ((old & 0xFFFF0000u) | w);
}
#endif

#if __has_builtin(__builtin_amdgcn_cvt_pk_f32_fp8)
__device__ inline void upk_fp8x4(u32 w, float* x){
  auto a0 = __builtin_amdgcn_cvt_pk_f32_fp8((int)w, false);
  auto a1 = __builtin_amdgcn_cvt_pk_f32_fp8((int)w, true);
  x[0] = a0[0]; x[1] = a0[1]; x[2] = a1[0]; x[3] = a1[1];
}
#else
__device__ inline float fp8_1(u32 byte){
  u32 s = (byte & 0x80u) << 24;
  u32 E = (byte >> 3) & 15u, M = byte & 7u;
  union{u32 u; float f;} v;
  if (E == 0){ v.f = (float)M * (1.0f/512.0f); v.u |= s; }
  else v.u = s | ((E + 120u) << 23) | (M << 20);
  return v.f;
}
__device__ inline void upk_fp8x4(u32 w, float* x){
  x[0] = fp8_1(w & 255u); x[1] = fp8_1((w >> 8) & 255u);
  x[2] = fp8_1((w >> 16) & 255u); x[3] = fp8_1(w >> 24);
}
#endif

// ---------------- weight prep ----------------
__global__ __launch_bounds__(256) void prep_w_k(const float* __restrict__ w2,
    const float* __restrict__ w1, u8* __restrict__ w2p, u16* __restrict__ w1c){
  int bidx = blockIdx.x;
  if (bidx < 25){
    int tap = bidx;
    int i = threadIdx.x;
    int oc = i >> 3, q = i & 7, ic0 = q * 4;
    float v[4];
    #pragma unroll
    for (int j = 0; j < 4; ++j)
      v[j] = (oc < MC && ic0 + j < MC) ? w2[(oc*MC + ic0 + j)*25 + tap] : 0.f;
    u32 w = pk_fp8<false>(v[0], v[1], 0u);
    w = pk_fp8<true>(v[2], v[3], w);
    int lo = ((oc << 5) + (q << 2)) ^ ((oc & 7) << 4);
    *(u32*)(w2p + tap*1024 + lo) = w;
  } else {
    for (int i = threadIdx.x; i < 2560; i += 256){
      int dy = i >> 9; int rem = i & 511; int oc = rem >> 4; int k = rem & 15;
      int dx = k >> 1, c = k & 1;
      float v = (oc < MC && dx < 5) ? w1[(oc*2 + c)*25 + dy*5 + dx] : 0.f;
      int byteoff = dy*1024 + (((oc<<5) + (k<<1)) ^ ((oc&7)<<4));
      *(u16*)((char*)w1c + byteoff) = f2bf(v);
    }
  }
}

// ---------------- kernel 1: row norms + bf16 conversion (PRE-SWIZZLED output) ----------------
__global__ __launch_bounds__(256) void row_norms_k(const float* __restrict__ q, const float* __restrict__ k,
    float* __restrict__ qq, float* __restrict__ kk,
    u16* __restrict__ qb16, u16* __restrict__ kb16){
  int wave = blockIdx.x * 4 + (threadIdx.x >> 6);
  int lane = threadIdx.x & 63;
  const float* src; float* dst; u16* bdst; int row;
  if (wave < NB * TT) { src = q; dst = qq; bdst = qb16; row = wave; }
  else                { src = k; dst = kk; bdst = kb16; row = wave - NB * TT; }
  const float4* p = (const float4*)(src + (size_t)row * DK);
  char* ob = (char*)(bdst + (size_t)row * DK);
  int key = (row & 7) << 4;
  float s = 0.f;
  {
    float4 a = p[2*lane], b2 = p[2*lane + 1];
    s += a.x*a.x + a.y*a.y + a.z*a.z + a.w*a.w;
    s += b2.x*b2.x + b2.y*b2.y + b2.z*b2.z + b2.w*b2.w;
    uint4 st;
    st.x = pack2bf(a.x, a.y);  st.y = pack2bf(a.z, a.w);
    st.z = pack2bf(b2.x, b2.y); st.w = pack2bf(b2.z, b2.w);
    *(uint4*)(ob + ((lane << 4) ^ key)) = st;
  }
  if (lane < 32){
    int g = 64 + lane;
    float4 a = p[2*g], b2 = p[2*g + 1];
    s += a.x*a.x + a.y*a.y + a.z*a.z + a.w*a.w;
    s += b2.x*b2.x + b2.y*b2.y + b2.z*b2.z + b2.w*b2.w;
    uint4 st;
    st.x = pack2bf(a.x, a.y);  st.y = pack2bf(a.z, a.w);
    st.z = pack2bf(b2.x, b2.y); st.w = pack2bf(b2.z, b2.w);
    *(uint4*)(ob + ((g << 4) ^ key)) = st;
  }
  #pragma unroll
  for (int o = 32; o; o >>= 1) s += __shfl_xor(s, o);
  if (lane == 0) dst[row] = s;
}

// ---------------- kernel 2: cdist via bf16 MFMA, async linear staging, XCD-grouped grid ----------------
__global__ __launch_bounds__(256) void cdist_mfma_k(
    const u16* __restrict__ Qb16, const u16* __restrict__ Kb16,
    const float* __restrict__ qq, const float* __restrict__ kk,
    const int* __restrict__ qlen, const int* __restrict__ klen,
    const float* __restrict__ qR, const float* __restrict__ kR,
    float* __restrict__ Dout, u32* __restrict__ inb){
  __shared__ __align__(16) char qs[32 * 1536];
  __shared__ __align__(16) char ksm[128 * 256];
  int bid = blockIdx.x;
  // XCD bid%8 owns batches 8k..8k+7; the 4 row-tiles of one batch share an XCD (L2 K reuse)
  int b  = ((bid & 7) << 3) + (bid >> 5);
  int rt = (bid >> 3) & 3;
  int r0 = rt * 32;
  int tid = threadIdx.x;
  int lane = tid & 63, w = tid >> 6;
  int hi = lane >> 5, l31 = lane & 31;
  const char* Qg = (const char*)(Qb16 + ((size_t)b * TT + r0) * DK);
  const char* Kg = (const char*)(Kb16 + (size_t)b * TT * DK);
#ifdef HAVE_GLDS
  #pragma unroll
  for (int i = 0; i < 12; ++i){
    int gb = (i*4 + w) << 6;
    __builtin_amdgcn_global_load_lds((const u32*)(Qg + ((gb + lane) << 4)),
                                     (u32*)(qs + (gb << 4)), 16, 0, 0);
  }
#else
  for (int idx = tid; idx < 3072; idx += 256)
    *(uint4*)(qs + idx*16) = *(const uint4*)(Qg + idx*16);
#endif
  int col = w * 32 + l31;
  f32x16 acc;
  #pragma unroll
  for (int r = 0; r < 16; ++r) acc[r] = 0.f;
  for (int kc = 0; kc < DK; kc += 128){
    __syncthreads();
#ifdef HAVE_GLDS
    const char* Ks = Kg + kc*2;
    #pragma unroll
    for (int i = 0; i < 8; ++i){
      int gb = (i*4 + w) << 6;
      int g = gb + lane;
      __builtin_amdgcn_global_load_lds((const u32*)(Ks + (g >> 4)*1536 + ((g & 15) << 4)),
                                       (u32*)(ksm + (gb << 4)), 16, 0, 0);
    }
#else
    for (int idx = tid; idx < 2048; idx += 256){
      int c = idx >> 4, j = idx & 15;
      *(uint4*)(ksm + idx*16) = *(const uint4*)(Kg + c*1536 + kc*2 + j*16);
    }
#endif
    __syncthreads();
    #pragma unroll
    for (int k8 = 0; k8 < 8; ++k8){
      bf16x8 a  = *(const bf16x8*)(qs  + l31 * 1536 + (((kc + k8*16 + hi*8) * 2) ^ ((l31 & 7) << 4)));
      bf16x8 bv = *(const bf16x8*)(ksm + col * 256  + (((k8*16 + hi*8) * 2) ^ ((col & 7) << 4)));
      acc = __builtin_amdgcn_mfma_f32_32x32x16_bf16(a, bv, acc, 0, 0, 0);
    }
  }
  int ql = qlen[b], kl = klen[b];
  float kkv = kk[b * TT + col];
  float krv = kR[b * TT + col];
  bool cm = col < kl;
  #pragma unroll
  for (int r = 0; r < 16; ++r){
    int row = r0 + (r & 3) + 8 * (r >> 2) + 4 * hi;
    float qqv = qq[b * TT + row];
    float sq = qqv + kkv - 2.f * acc[r];
    float d = sqrtf(fmaxf(sq, 1e-12f));
    bool m = (row < ql) && cm;
    float dm = m ? d : 0.f;
    float pm = m ? fabsf(qR[b * TT + row] - krv) : 0.f;
    Dout[(((size_t)b * TT + row) << 7) + col] = dm;
    inb[(((size_t)b * TT + row) << 7) + col] = pack2bf(dm, pm);
  }
}

// ---------------- fused conv1+conv2 ----------------
#define C1_ROWW 136
#define C2_IN_ROWB 4224                 // 132 px * 32 B
#define F_INB_BYTES (16*C1_ROWW*4)      // 8704
#define F_C2_OFF F_INB_BYTES
#define F_SMEM (F_INB_BYTES + 12*C2_IN_ROWB)   // 59392

__global__ __launch_bounds__(512, 4) void conv12_mfma_k(
    const u32* __restrict__ inb, const u8* __restrict__ w2p, const u16* __restrict__ w1c,
    const float* __restrict__ b1, const float* __restrict__ b2, u8* __restrict__ act2){
  __shared__ __align__(16) char smem[F_SMEM];
  u32* ilds = (u32*)smem;
  char* c2in = smem + F_C2_OFF;
  int o  = blockIdx.x;
  int yg = ((o & 7) << 1) + (o >> 3);
  int bb = blockIdx.y;
  int y0 = yg * 8;
  int tid = threadIdx.x;
  for (int i = tid; i < 16*C1_ROWW; i += 512){
    int r = i / C1_ROWW, xi = i - r * C1_ROWW;
    int gy = y0 - 4 + r, gx = xi - 2;
    u32 v = 0;
    if ((unsigned)gy < 128u && (unsigned)gx < 128u)
      v = inb[(((size_t)bb * 128 + gy) << 7) + gx];
    ilds[r * C1_ROWW + xi] = v;
  }
  for (int i = tid; i < 96; i += 512){
    int r = i >> 3; int rem = i & 7; int ci = rem >> 1; int h = rem & 1;
    int lx = (ci < 2) ? ci : (128 + ci);
    int addr = r*C2_IN_ROWB + (((lx << 5) + (h << 4)) ^ ((lx & 7) << 4));
    *(uint4*)(c2in + addr) = make_uint4(0,0,0,0);
  }
  int lane = tid & 63, w = tid >> 6;
  int hi = lane >> 5, l31 = lane & 31;
  int aSwz = ((l31 << 5) + (hi << 4)) ^ ((l31 & 7) << 4);
  bf16x8 afr[5];
  #pragma unroll
  for (int dy = 0; dy < 5; ++dy)
    afr[dy] = *(const bf16x8*)((const char*)w1c + dy*1024 + aSwz);
  float b1v[16];
  #pragma unroll
  for (int r = 0; r < 16; ++r){
    int oc = (r & 3) + 8*(r >> 2) + 4*hi;
    b1v[r] = (oc < MC) ? b1[oc] : 0.f;
  }
  __syncthreads();
  for (int rep = 0; rep < 2; ++rep){
    if (rep == 1 && w >= 4) break;
    int idx = (rep == 0) ? w : (8 + w);
    int gy = y0 - 2 + idx;
    bool oob = (unsigned)gy >= 128u;
    #pragma unroll
    for (int t = 0; t < 4; ++t){
      int px = t*32 + l31;
      u32 words[4];
      if (!oob){
        f32x16 acc;
        #pragma unroll
        for (int r = 0; r < 16; ++r) acc[r] = 0.f;
        #pragma unroll
        for (int dy = 0; dy < 5; ++dy){
          const u32* rp = &ilds[(idx + dy)*C1_ROWW + px + hi*4];
          union { u32 uw[4]; bf16x8 v; } ub;
          ub.uw[0] = rp[0]; ub.uw[1] = rp[1]; ub.uw[2] = rp[2]; ub.uw[3] = rp[3];
          acc = __builtin_amdgcn_mfma_f32_32x32x16_bf16(afr[dy], ub.v, acc, 0, 0, 0);
        }
        #pragma unroll
        for (int q = 0; q < 4; ++q){
          u32 word = pk_fp8<false>(fmaxf(acc[4*q+0]+b1v[4*q+0], 0.f),
                                   fmaxf(acc[4*q+1]+b1v[4*q+1], 0.f), 0u);
          word = pk_fp8<true>(fmaxf(acc[4*q+2]+b1v[4*q+2], 0.f),
                              fmaxf(acc[4*q+3]+b1v[4*q+3], 0.f), word);
          words[q] = word;
        }
      } else {
        words[0] = words[1] = words[2] = words[3] = 0u;
      }
      int lx = px + 2;
      #pragma unroll
      for (int q = 0; q < 4; ++q){
        int ic = q*8 + hi*4;
        int addr = idx*C2_IN_ROWB + (((lx << 5) + ic) ^ ((lx & 7) << 4));
        *(u32*)(c2in + addr) = words[q];
      }
    }
  }
  __syncthreads();
  f32x16 acc[4];
  #pragma unroll
  for (int t = 0; t < 4; ++t)
    #pragma unroll
    for (int r = 0; r < 16; ++r) acc[t][r] = 0.f;
  #pragma unroll
  for (int dy = 0; dy < 5; ++dy){
    const char* rowp = c2in + (w + dy)*C2_IN_ROWB;
    ll2 aw[5];
    #pragma unroll
    for (int dx = 0; dx < 5; ++dx)
      aw[dx] = *(const ll2*)(w2p + (dy*5 + dx)*1024 + aSwz);
#ifdef HAVE_MXFP8
    union U8x { struct { ll2 lo, hi; } p; i32x8 v; };
    U8x a01, a23, a4z;
    ll2 zz; zz.x = 0; zz.y = 0;
    a01.p.lo = aw[0]; a01.p.hi = aw[1];
    a23.p.lo = aw[2]; a23.p.hi = aw[3];
    a4z.p.lo = aw[4]; a4z.p.hi = zz;
    #pragma unroll
    for (int t = 0; t < 4; ++t){
      int pxb = t*32 + l31;
      ll2 bl[5];
      #pragma unroll
      for (int dx = 0; dx < 5; ++dx){
        int px2 = pxb + dx;
        int boff = ((px2 << 5) + (hi << 4)) ^ ((px2 & 7) << 4);
        bl[dx] = *(const ll2*)(rowp + boff);
      }
      U8x b01, b23, b4d;
      b01.p.lo = bl[0]; b01.p.hi = bl[1];
      b23.p.lo = bl[2]; b23.p.hi = bl[3];
      b4d.p.lo = bl[4]; b4d.p.hi = bl[4];
      acc[t] = __builtin_amdgcn_mfma_scale_f32_32x32x64_f8f6f4(
                 a01.v, b01.v, acc[t], 0, 0, 0, 0x7F7F7F7F, 0, 0x7F7F7F7F);
      acc[t] = __builtin_amdgcn_mfma_scale_f32_32x32x64_f8f6f4(
                 a23.v, b23.v, acc[t], 0, 0, 0, 0x7F7F7F7F, 0, 0x7F7F7F7F);
      acc[t] = __builtin_amdgcn_mfma_scale_f32_32x32x64_f8f6f4(
                 a4z.v, b4d.v, acc[t], 0, 0, 0, 0x7F7F7F7F, 0, 0x7F7F7F7F);
    }
#else
    #pragma unroll
    for (int dx = 0; dx < 5; ++dx){
      ll2 a = aw[dx];
      #pragma unroll
      for (int t = 0; t < 4; ++t){
        int px2 = t*32 + l31 + dx;
        int boff = ((px2 << 5) + (hi << 4)) ^ ((px2 & 7) << 4);
        ll2 b = *(const ll2*)(rowp + boff);
        acc[t] = __builtin_amdgcn_mfma_f32_32x32x16_fp8_fp8(a.x, b.x, acc[t], 0, 0, 0);
        acc[t] = __builtin_amdgcn_mfma_f32_32x32x16_fp8_fp8(a.y, b.y, acc[t], 0, 0, 0);
      }
    }
#endif
  }
  float b2v[16];
  #pragma unroll
  for (int r = 0; r < 16; ++r){
    int oc = (r & 3) + 8*(r >> 2) + 4*hi;
    b2v[r] = (oc < MC) ? b2[oc] : 0.f;
  }
  __syncthreads();
  int wbase = w * 4096;
  #pragma unroll
  for (int t = 0; t < 4; ++t){
    int px = t*32 + l31;
    #pragma unroll
    for (int q = 0; q < 4; ++q){
      float v0 = fmaxf(acc[t][4*q+0] + b2v[4*q+0], 0.f);
      float v1 = fmaxf(acc[t][4*q+1] + b2v[4*q+1], 0.f);
      float v2 = fmaxf(acc[t][4*q+2] + b2v[4*q+2], 0.f);
      float v3 = fmaxf(acc[t][4*q+3] + b2v[4*q+3], 0.f);
      u32 word = pk_fp8<false>(v0, v1, 0u);
      word = pk_fp8<true>(v2, v3, word);
      int addr = wbase + (((px<<5) + (q<<3) + (hi<<2)) ^ (((px>>2)&3)<<3));
      *(u32*)(c2in + addr) = word;
    }
  }
  int y = y0 + w;
  #pragma unroll
  for (int p = 0; p < 8; ++p){
    int x = p*16 + (lane >> 2), cg = lane & 3;
    int addr = wbase + (((x<<5) + (cg<<3)) ^ (((x>>2)&3)<<3));
    uint2 v = *(const uint2*)(c2in + addr);
    *(uint2*)(act2 + ((((size_t)bb*128 + y)*128 + x) << 5) + cg*8) = v;
  }
}

// ---------------- conv3 + mask + row softmax + A write + row D*A ----------------
// 2 rows per block; thread = (row r, px, half); half owns 16 channels (one uint4)
__global__ __launch_bounds__(512) void conv3sm_k(const u8* __restrict__ act2,
    const float* __restrict__ w3, const float* __restrict__ b3, const float* __restrict__ Dbuf,
    const int* __restrict__ qlen, const int* __restrict__ klen,
    float* __restrict__ Aout, float* __restrict__ rowsum, int b0){
  __shared__ float wlds[9][32];
  __shared__ float ex0[512], ex2[512];
  __shared__ float redm[8], reds[8], redd[8];
  int o  = blockIdx.x;                    // 0..63
  int ip = ((o & 7) << 3) + (o >> 3);     // XCD-chunked row-pair index
  int bb = blockIdx.y;
  int b  = b0 + bb;
  int tid = threadIdx.x;
  for (int idx = tid; idx < 288; idx += 512){
    int tap = idx >> 5, c = idx & 31;
    wlds[tap][c] = (c < MC) ? w3[c * 9 + tap] : 0.f;
  }
  __syncthreads();
  int r  = tid >> 8;          // row within pair
  int t  = tid & 255;
  int px = t >> 1, half = t & 1;
  int i  = ip * 2 + r;
  int wv = tid >> 6;          // wave 0..7 (waves 0-3 = row 0, 4-7 = row 1)
  float T0 = 0.f, T1 = 0.f, T2 = 0.f;
  #pragma unroll
  for (int dy = 0; dy < 3; ++dy){
    int gy = i - 1 + dy;
    uint4 v = make_uint4(0, 0, 0, 0);
    if ((unsigned)gy < 128u)
      v = *(const uint4*)(act2 + ((((size_t)bb*128 + gy)*128 + px) << 5) + half*16);
    float x[16];
    upk_fp8x4(v.x, x); upk_fp8x4(v.y, x + 4);
    upk_fp8x4(v.z, x + 8); upk_fp8x4(v.w, x + 12);
    const float* w0p = &wlds[dy*3 + 0][half*16];
    const float* w1p = &wlds[dy*3 + 1][half*16];
    const float* w2q = &wlds[dy*3 + 2][half*16];
    #pragma unroll
    for (int c = 0; c < 16; ++c){
      T0 = fmaf(x[c], w0p[c], T0);
      T1 = fmaf(x[c], w1p[c], T1);
      T2 = fmaf(x[c], w2q[c], T2);
    }
  }
  ex0[tid] = T0; ex2[tid] = T2;
  __syncthreads();
  float acc = T1;
  if (px > 0)   acc += ex0[tid - 2];
  if (px < 127) acc += ex2[tid + 2];
  acc += __shfl_xor(acc, 1);      // combine the two 16-ch halves
  acc += b3[0];
  float Dv = Dbuf[(((size_t)b * 128 + i) << 7) + px];
  bool m = (i < qlen[b]) && (px < klen[b]);
  float xv = m ? -(acc + Dv) : -100.f;
  float mx = xv;
  #pragma unroll
  for (int o2 = 32; o2; o2 >>= 1) mx = fmaxf(mx, __shfl_xor(mx, o2));
  if ((tid & 63) == 0) redm[wv] = mx;
  __syncthreads();
  int rb4 = r << 2;
  mx = fmaxf(fmaxf(redm[rb4], redm[rb4+1]), fmaxf(redm[rb4+2], redm[rb4+3]));
  float e = __expf(xv - mx);
  float s  = e;
  float de = Dv * e;
  #pragma unroll
  for (int o2 = 32; o2; o2 >>= 1){ s += __shfl_xor(s, o2); de += __shfl_xor(de, o2); }
  if ((tid & 63) == 0){ reds[wv] = s; redd[wv] = de; }
  __syncthreads();
  float s4 = (reds[rb4] + reds[rb4+1]) + (reds[rb4+2] + reds[rb4+3]);
  float a = e * 2.0f / s4;            // each px counted twice (half 0/1)
  if (half == 0) Aout[(((size_t)b * 128 + i) << 7) + px] = a;
  if (t == 0){
    float d4 = (redd[rb4] + redd[rb4+1]) + (redd[rb4+2] + redd[rb4+3]);
    rowsum[b * TT + i] = d4 / s4;
  }
}

// ---------------- dis reduce ----------------
__global__ __launch_bounds__(128) void dis_k(const float* __restrict__ rowsum, float* __restrict__ out){
  int b = blockIdx.x, tid = threadIdx.x;
  float v = rowsum[b * TT + tid];
  #pragma unroll
  for (int o = 32; o; o >>= 1) v += __shfl_xor(v, o);
  __shared__ float red[2];
  if ((tid & 63) == 0) red[tid >> 6] = v;
  __syncthreads();
  if (tid == 0) out[b] = (red[0] + red[1]) * (1.0f / 128.0f);
}

extern "C" void kernel_launch(void* const* d_in, const int* in_sizes, int n_in,
                              void* d_out, int out_size, void* d_ws, size_t ws_size,
                              hipStream_t stream){
  const float* q_seq = (const float*)d_in[0];
  const int*   q_len = (const int*)d_in[1];
  const float* q_R   = (const float*)d_in[2];
  const float* k_seq = (const float*)d_in[3];
  const int*   k_len = (const int*)d_in[4];
  const float* k_R   = (const float*)d_in[5];
  const float* c1w   = (const float*)d_in[6];
  const float* c1b   = (const float*)d_in[7];
  const float* c2w   = (const float*)d_in[8];
  const float* c2b   = (const float*)d_in[9];
  const float* c3w   = (const float*)d_in[10];
  const float* c3b   = (const float*)d_in[11];
  float* out = (float*)d_out;

  char* base = (char*)d_ws;
  size_t off = 0;
  auto take = [&](size_t bytes)->char*{
    char* p = base + off;
    off = (off + bytes + 255) & ~(size_t)255;
    return p;
  };
  float* Dbuf   = (float*)take((size_t)NB * TT * TT * 4);
  float* qq     = (float*)take((size_t)NB * TT * 4);
  float* kkn    = (float*)take((size_t)NB * TT * 4);
  float* rowsum = (float*)take((size_t)NB * TT * 4);
  u32*   inb    = (u32*)  take((size_t)NB * TT * TT * 4);
  u8*    w2p    = (u8*)   take(25 * 1024);
  u16*   w1c    = (u16*)  take(5 * 1024);
  u16*   qb16   = (u16*)  take((size_t)NB * TT * DK * 2);
  u16*   kb16   = (u16*)  take((size_t)NB * TT * DK * 2);
  size_t fixed = off;
  int BCH = 64;
  while (BCH > 1 && fixed + (size_t)BCH * TT * TT * 32 + 1024 > ws_size) BCH >>= 1;
  u8* act2 = (u8*)take((size_t)BCH * TT * TT * 32);

  prep_w_k<<<26, 256, 0, stream>>>(c2w, c1w, w2p, w1c);
  row_norms_k<<<4096, 256, 0, stream>>>(q_seq, k_seq, qq, kkn, qb16, kb16);
  cdist_mfma_k<<<256, 256, 0, stream>>>(qb16, kb16, qq, kkn, q_len, k_len, q_R, k_R, Dbuf, inb);
  for (int b0 = 0; b0 < NB; b0 += BCH){
    int nb = BCH;
    conv12_mfma_k<<<dim3(16, nb), 512, 0, stream>>>(inb + (size_t)b0 * TT * TT, w2p, w1c, c1b, c2b, act2);
    conv3sm_k<<<dim3(64, nb), 512, 0, stream>>>(act2, c3w, c3b, Dbuf, q_len, k_len, out, rowsum, b0);
  }
  dis_k<<<NB, 128, 0, stream>>>(rowsum, out + (size_t)NB * TT * TT);
}